// Round 3
// baseline (2889.503 us; speedup 1.0000x reference)
//
#include <hip/hip_runtime.h>
#include <hip/hip_bf16.h>

typedef __bf16 bf16_t;
typedef unsigned short u16;
typedef short short8 __attribute__((ext_vector_type(8)));
typedef float f32x4 __attribute__((ext_vector_type(4)));

#define ABITS 8             // 256 dst-rows per bucket
#define AROWS 256
#define KMAX 1280           // >= ceil(300032/256); scans use 5 entries/thread
#define TILE 8192

__device__ inline short f2bs(float v) {
    bf16_t h = (bf16_t)v;
    return __builtin_bit_cast(short, h);
}
__device__ inline float uif(unsigned u) { return __builtin_bit_cast(float, u); }

// ---------------- prep (cvt + weights) + bucket_count (LDS hist), one launch ----------------
// wh mats (transposed [n*64+k]): 0..5 Wn[l*3+e]; 6,7 WrB[l]=Wr[l,0];
// 8,9 WrA[l]=Wr[l,1]+Wr[l,2] (f32 pre-sum); 10 W_out.
__global__ __launch_bounds__(256) void prep_count(
    const float* __restrict__ xA, const float* __restrict__ xB,
    const float* __restrict__ Wn, const float* __restrict__ Wr,
    const float* __restrict__ Wout,
    u16* __restrict__ plane0, u16* __restrict__ wh,
    const int* __restrict__ d0, const int* __restrict__ d1,
    const int* __restrict__ d2, int* __restrict__ ghist,
    int NA, int NB, int E, int total, int K) {
    __shared__ int h[KMAX];
    int nA4 = NA * 16, nB4 = NB * 16;
    int bA = (nA4 + 255) / 256, bB = (nB4 + 255) / 256;
    int bi = blockIdx.x;
    int tid = threadIdx.x;
    if (bi < bA + bB) {
        const float* in = (bi < bA) ? xA : xB;
        u16* out = (bi < bA) ? plane0 : plane0 + (size_t)NA * 64;
        int i = (bi < bA ? bi : bi - bA) * 256 + tid;
        int n4 = (bi < bA) ? nA4 : nB4;
        if (i >= n4) return;
        float4 v = ((const float4*)in)[i];
        u16 o[4];
        o[0] = (u16)f2bs(v.x); o[1] = (u16)f2bs(v.y);
        o[2] = (u16)f2bs(v.z); o[3] = (u16)f2bs(v.w);
        *(uint2*)(out + (size_t)i * 4) = *(uint2*)o;
        return;
    }
    if (bi < bA + bB + 11) {
        int mat = bi - bA - bB;      // 0..10
        u16* dstp = wh + (size_t)mat * 4096;
        for (int i = tid; i < 4096; i += 256) {
            int k = i >> 6, n = i & 63;
            float v;
            if (mat < 6) v = Wn[(size_t)mat * 4096 + i];
            else if (mat < 8) v = Wr[(size_t)((mat - 6) * 3 + 0) * 4096 + i];
            else if (mat < 10) v = Wr[(size_t)((mat - 8) * 3 + 1) * 4096 + i]
                                 + Wr[(size_t)((mat - 8) * 3 + 2) * 4096 + i];
            else v = Wout[i];
            dstp[n * 64 + k] = (u16)f2bs(v);
        }
        return;
    }
    // ---- bucket_count portion (512 blocks, grid-stride, LDS hist) ----
    int cb = bi - (bA + bB + 11);
    for (int i = tid; i < KMAX; i += 256) h[i] = 0;
    __syncthreads();
    for (int i = cb * 256 + tid; i < total; i += 512 * 256) {
        int g;
        if (i < E) g = d0[i];
        else if (i < 2 * E) g = NB + d1[i - E];
        else g = NB + NA + d2[i - 2 * E];
        atomicAdd(&h[g >> ABITS], 1);
    }
    __syncthreads();
    for (int i = tid; i < K; i += 256)
        if (h[i]) atomicAdd(&ghist[i], h[i]);
}

// ---- exclusive scan over K bucket sums (K <= KMAX), one block, 5/thread ----
__global__ __launch_bounds__(256) void bucket_scan(const int* __restrict__ ghist,
                                                   int* __restrict__ bbase,
                                                   int* __restrict__ gcursor,
                                                   int K, int total) {
    __shared__ int ssum[256];
    int tid = threadIdx.x;
    int v[5]; int s = 0;
#pragma unroll
    for (int j = 0; j < 5; j++) {
        int i = tid * 5 + j;
        v[j] = s;
        s += (i < K) ? ghist[i] : 0;
    }
    ssum[tid] = s; __syncthreads();
    for (int off = 1; off < 256; off <<= 1) {
        int t = (tid >= off) ? ssum[tid - off] : 0; __syncthreads();
        ssum[tid] += t; __syncthreads();
    }
    int exc = tid ? ssum[tid - 1] : 0;
#pragma unroll
    for (int j = 0; j < 5; j++) {
        int i = tid * 5 + j;
        if (i < K) { bbase[i] = exc + v[j]; gcursor[i] = exc + v[j]; }
    }
    if (tid == 255) bbase[K] = total;
}

// pairs entry: packed = tb<<25 | ((g & 255) << 17) | src
// (src < 2^17, bucket = g >> 8, tb = src-table selector: 1 -> B plane)
__global__ __launch_bounds__(256) void partition_kernel(
    const int* __restrict__ s0, const int* __restrict__ d0,
    const int* __restrict__ s1, const int* __restrict__ d1,
    const int* __restrict__ s2, const int* __restrict__ d2,
    int* __restrict__ gcursor, int* __restrict__ pairs,
    int NB, int NA, int E, int total) {
    __shared__ int hist[KMAX];
    __shared__ int gbase[KMAX];
    __shared__ int ssum[256];
    __shared__ int2 buf[TILE];   // {packed, bkt}
    int tid = threadIdx.x;
    for (int tile = blockIdx.x * TILE; tile < total; tile += gridDim.x * TILE) {
        for (int i = tid; i < KMAX; i += 256) hist[i] = 0;
        __syncthreads();
        int cnt = min(TILE, total - tile);
        int mybkt[32], mypk[32], myrank[32];
#pragma unroll
        for (int j = 0; j < 32; j++) {
            int idx = tile + j * 256 + tid;
            int g = -1, s = 0, tb = 0;
            if (idx < total) {
                if (idx < E) { s = s0[idx]; g = d0[idx]; tb = 0; }
                else if (idx < 2 * E) { s = s1[idx - E]; g = NB + d1[idx - E]; tb = 1; }
                else { s = s2[idx - 2 * E]; g = NB + NA + d2[idx - 2 * E]; tb = 0; }
            }
            if (g >= 0) {
                mybkt[j] = g >> ABITS;
                mypk[j] = (tb << 25) | ((g & (AROWS - 1)) << 17) | s;
                myrank[j] = atomicAdd(&hist[mybkt[j]], 1);
            } else mybkt[j] = -1;
        }
        __syncthreads();
        int l[5]; int base5 = tid * 5; int ts = 0;
#pragma unroll
        for (int j = 0; j < 5; j++) { l[j] = hist[base5 + j]; ts += l[j]; }
        ssum[tid] = ts; __syncthreads();
        for (int off = 1; off < 256; off <<= 1) {
            int t = (tid >= off) ? ssum[tid - off] : 0; __syncthreads();
            ssum[tid] += t; __syncthreads();
        }
        int exc = tid ? ssum[tid - 1] : 0;
#pragma unroll
        for (int j = 0; j < 5; j++) {
            hist[base5 + j] = exc;
            if (l[j]) gbase[base5 + j] = atomicAdd(&gcursor[base5 + j], l[j]);
            exc += l[j];
        }
        __syncthreads();
#pragma unroll
        for (int j = 0; j < 32; j++) {
            if (mybkt[j] >= 0)
                buf[hist[mybkt[j]] + myrank[j]] = make_int2(mypk[j], mybkt[j]);
        }
        __syncthreads();
        for (int i = tid; i < cnt; i += 256) {
            int2 p = buf[i];
            pairs[gbase[p.y] + (i - hist[p.y])] = p.x;
        }
        __syncthreads();
    }
}

// ---------------- edge-major aggregate: bucket per block, LDS f32 accumulator ----------------
// Block b owns dst rows [b*256, b*256+256). acc[256][65] f32 (+1 pad: ds_add bank
// = (lr + 8*fl + j) mod 32, spreads with the random row). Each 8-lane octet streams
// a contiguous chunk of the bucket's edges: per edge one uint4 row load per lane
// (128B/row/octet), 8 LDS float atomicAdds at immediate offsets, one predicated
// count add. No per-dst CSR, no per-row tail waste.
__global__ __launch_bounds__(512) void aggregate(
    const u16* __restrict__ plane, const int* __restrict__ pairs,
    const int* __restrict__ bbase,
    u16* __restrict__ meanB, u16* __restrict__ meanA1, u16* __restrict__ meanA2,
    int NB, int NA, int M) {
    __shared__ float accS[AROWS * 65];
    __shared__ float cntS[AROWS];
    int b = blockIdx.x, t = threadIdx.x;
    float4* az = (float4*)accS;
    for (int i = t; i < AROWS * 65 / 4; i += 512) az[i] = make_float4(0.f, 0.f, 0.f, 0.f);
    if (t < AROWS) cntS[t] = 0.f;
    __syncthreads();

    int p0 = bbase[b], p1 = bbase[b + 1];
    int n = p1 - p0;
    int oct = t >> 3, fl = t & 7;          // 64 octets x 8 lanes
    unsigned fo = (unsigned)(fl << 4);
    const char* pA = (const char*)plane;
    const char* pB = pA + ((size_t)NA << 7);

    int chunk = (n + 63) >> 6;
    int e0 = p0 + oct * chunk;
    int e1 = min(e0 + chunk, p1);

#define ROWP(c) ((((c) & (1u << 25)) ? pB : pA) + ((((c) & 0x1FFFFu) << 7) | fo))
#define CONSUME(c, u)                                                     \
    do {                                                                  \
        int lr_ = ((c) >> 17) & (AROWS - 1);                              \
        float* ap_ = accS + lr_ * 65 + (fl << 3);                         \
        if (fl == 0) atomicAdd(&cntS[lr_], 1.0f);                         \
        atomicAdd(&ap_[0], uif((u).x << 16));                             \
        atomicAdd(&ap_[1], uif((u).x & 0xFFFF0000u));                     \
        atomicAdd(&ap_[2], uif((u).y << 16));                             \
        atomicAdd(&ap_[3], uif((u).y & 0xFFFF0000u));                     \
        atomicAdd(&ap_[4], uif((u).z << 16));                             \
        atomicAdd(&ap_[5], uif((u).z & 0xFFFF0000u));                     \
        atomicAdd(&ap_[6], uif((u).w << 16));                             \
        atomicAdd(&ap_[7], uif((u).w & 0xFFFF0000u));                     \
    } while (0)

    int e = e0;
    if (e + 3 < e1) {
        unsigned c0 = (unsigned)pairs[e],     c1 = (unsigned)pairs[e + 1];
        unsigned c2 = (unsigned)pairs[e + 2], c3 = (unsigned)pairs[e + 3];
        while (e + 7 < e1) {
            uint4 u0 = *(const uint4*)ROWP(c0);
            uint4 u1 = *(const uint4*)ROWP(c1);
            uint4 u2 = *(const uint4*)ROWP(c2);
            uint4 u3 = *(const uint4*)ROWP(c3);
            unsigned n0 = (unsigned)pairs[e + 4], n1 = (unsigned)pairs[e + 5];
            unsigned n2 = (unsigned)pairs[e + 6], n3 = (unsigned)pairs[e + 7];
            CONSUME(c0, u0); CONSUME(c1, u1); CONSUME(c2, u2); CONSUME(c3, u3);
            c0 = n0; c1 = n1; c2 = n2; c3 = n3;
            e += 4;
        }
        {   // drain the pipelined quad
            uint4 u0 = *(const uint4*)ROWP(c0);
            uint4 u1 = *(const uint4*)ROWP(c1);
            uint4 u2 = *(const uint4*)ROWP(c2);
            uint4 u3 = *(const uint4*)ROWP(c3);
            CONSUME(c0, u0); CONSUME(c1, u1); CONSUME(c2, u2); CONSUME(c3, u3);
            e += 4;
        }
    }
    for (; e < e1; ++e) {
        unsigned c = (unsigned)pairs[e];
        uint4 u = *(const uint4*)ROWP(c);
        CONSUME(c, u);
    }
#undef CONSUME
#undef ROWP

    __syncthreads();
    // writeout: octet handles 4 rows; per row each lane packs its 8 feats -> uint4 store
    int gbase0 = b << ABITS;
#pragma unroll
    for (int r4 = 0; r4 < 4; ++r4) {
        int lr = oct * 4 + r4;
        int g = gbase0 + lr;
        if (g >= M) continue;
        float inv = 1.0f / fmaxf(cntS[lr], 1.0f);
        const float* ap = accS + lr * 65 + (fl << 3);
        u16 o[8];
#pragma unroll
        for (int j = 0; j < 8; j++) o[j] = (u16)f2bs(ap[j] * inv);
        u16* outp; int orow;
        if (g < NB) { outp = meanB; orow = g; }
        else if (g < NB + NA) { outp = meanA1; orow = g - NB; }
        else { outp = meanA2; orow = g - NB - NA; }
        *(uint4*)(outp + ((size_t)orow << 6) + (fl << 3)) = *(uint4*)o;
    }
}

// ---------------- fused linear body (bf16 in, MFMA, bf16 or f32 out) ----------------
// A[m=lane&15][k=(lane>>4)*8+j], B[k][n=lane&15] (pre-transposed),
// C/D row=(lane>>4)*4+reg, col=lane&15.
template <int NM, int RELU, int OUTF32>
__device__ __forceinline__ void lin_body(
    const u16* __restrict__ m0, const u16* __restrict__ m1,
    const u16* __restrict__ x,
    const u16* __restrict__ Wm0t, const u16* __restrict__ Wm1t,
    const u16* __restrict__ Wxt,
    const float* __restrict__ bias0, const float* __restrict__ bias1,
    void* __restrict__ outv, int nrows, int blk) {
    const int lane = threadIdx.x & 63;
    const int wave = threadIdx.x >> 6;
    const int row0 = blk * 64 + wave * 16;
    if (row0 >= nrows) return;
    const int r = lane & 15;
    const int q = lane >> 4;

    short8 wm0f[2][4], wm1f[2][4], wxf[2][4];
#pragma unroll
    for (int ks = 0; ks < 2; ks++) {
#pragma unroll
        for (int t = 0; t < 4; t++) {
            size_t widx = (size_t)(t * 16 + r) * 64 + ks * 32 + q * 8;
            if (NM >= 1) wm0f[ks][t] = *(const short8*)(Wm0t + widx);
            if (NM >= 2) wm1f[ks][t] = *(const short8*)(Wm1t + widx);
            wxf[ks][t] = *(const short8*)(Wxt + widx);
        }
    }

    f32x4 acc[4];
#pragma unroll
    for (int t = 0; t < 4; t++) {
        float bv = bias0[t * 16 + r];
        if (bias1) bv += bias1[t * 16 + r];
        acc[t][0] = bv; acc[t][1] = bv; acc[t][2] = bv; acc[t][3] = bv;
    }

    const int arow = row0 + r;
    const bool avalid = arow < nrows;
    short8 zf;
#pragma unroll
    for (int j = 0; j < 8; j++) zf[j] = 0;

    if (NM >= 1) {
#pragma unroll
        for (int ks = 0; ks < 2; ks++) {
            short8 af = avalid ? *(const short8*)(m0 + (size_t)arow * 64 + ks * 32 + q * 8) : zf;
#pragma unroll
            for (int t = 0; t < 4; t++)
                acc[t] = __builtin_amdgcn_mfma_f32_16x16x32_bf16(af, wm0f[ks][t], acc[t], 0, 0, 0);
        }
    }
    if (NM >= 2) {
#pragma unroll
        for (int ks = 0; ks < 2; ks++) {
            short8 af = avalid ? *(const short8*)(m1 + (size_t)arow * 64 + ks * 32 + q * 8) : zf;
#pragma unroll
            for (int t = 0; t < 4; t++)
                acc[t] = __builtin_amdgcn_mfma_f32_16x16x32_bf16(af, wm1f[ks][t], acc[t], 0, 0, 0);
        }
    }
#pragma unroll
    for (int ks = 0; ks < 2; ks++) {
        short8 xf = avalid ? *(const short8*)(x + (size_t)arow * 64 + ks * 32 + q * 8) : zf;
#pragma unroll
        for (int t = 0; t < 4; t++)
            acc[t] = __builtin_amdgcn_mfma_f32_16x16x32_bf16(xf, wxf[ks][t], acc[t], 0, 0, 0);
    }

#pragma unroll
    for (int t = 0; t < 4; t++) {
#pragma unroll
        for (int rr = 0; rr < 4; rr++) {
            int row = row0 + q * 4 + rr;
            if (row < nrows) {
                float v = acc[t][rr];
                if (RELU) v = fmaxf(v, 0.0f);
                if (OUTF32) ((float*)outv)[(size_t)row * 64 + t * 16 + r] = v;
                else ((u16*)outv)[(size_t)row * 64 + t * 16 + r] = (u16)f2bs(v);
            }
        }
    }
}

// one layer: B-phase blocks [0,blocksB), A-phase blocks [blocksB, ...)
__global__ __launch_bounds__(256) void layer_kernel(
    const u16* __restrict__ plane_in, u16* __restrict__ plane_out,
    const u16* __restrict__ meanB, const u16* __restrict__ meanA1,
    const u16* __restrict__ meanA2, const u16* __restrict__ wh,
    const float* __restrict__ bvec, int l, int NA, int NB, int blocksB) {
    if ((int)blockIdx.x < blocksB) {
        // new_B = mean(A->B)@Wn[l,0] + x_B@Wr[l,0] + b[l,0]
        lin_body<1, 0, 0>(meanB, nullptr, plane_in + (size_t)NA * 64,
                          wh + (size_t)(l * 3 + 0) * 4096, nullptr,
                          wh + (size_t)(6 + l) * 4096,
                          bvec + (size_t)(l * 3 + 0) * 64, nullptr,
                          plane_out + (size_t)NA * 64, NB, blockIdx.x);
    } else {
        // new_A = mean(B->A)@Wn[l,1] + mean(A->A)@Wn[l,2] + x_A@(Wr[l,1]+Wr[l,2]) + b[l,1]+b[l,2]
        lin_body<2, 0, 0>(meanA1, meanA2, plane_in,
                          wh + (size_t)(l * 3 + 1) * 4096, wh + (size_t)(l * 3 + 2) * 4096,
                          wh + (size_t)(8 + l) * 4096,
                          bvec + (size_t)(l * 3 + 1) * 64, bvec + (size_t)(l * 3 + 2) * 64,
                          plane_out, NA, blockIdx.x - blocksB);
    }
}

// head over NA+NB contiguous rows
__global__ __launch_bounds__(256) void head_kernel(
    const u16* __restrict__ plane_in, const u16* __restrict__ wh,
    const float* __restrict__ b_out, float* __restrict__ out, int nrows) {
    lin_body<0, 1, 1>(nullptr, nullptr, plane_in,
                      nullptr, nullptr, wh + (size_t)10 * 4096,
                      b_out, nullptr, out, nrows, blockIdx.x);
}

// ---------------- launch ----------------
extern "C" void kernel_launch(void* const* d_in, const int* in_sizes, int n_in,
                              void* d_out, int out_size, void* d_ws, size_t ws_size,
                              hipStream_t stream) {
    const float* xA_in = (const float*)d_in[0];
    const float* xB_in = (const float*)d_in[1];
    const float* Wn = (const float*)d_in[2];
    const float* Wr = (const float*)d_in[3];
    const float* b = (const float*)d_in[4];
    const float* W_out = (const float*)d_in[5];
    const float* b_out = (const float*)d_in[6];
    const int* src0 = (const int*)d_in[7];
    const int* dst0 = (const int*)d_in[8];
    const int* src1 = (const int*)d_in[9];
    const int* dst1 = (const int*)d_in[10];
    const int* src2 = (const int*)d_in[11];
    const int* dst2 = (const int*)d_in[12];

    const int NA = in_sizes[0] / 64;
    const int NB = in_sizes[1] / 64;
    const int E = in_sizes[7];
    const int M = NB + NA + NA;
    const int total = 3 * E;
    const int K = (M + AROWS - 1) >> ABITS;     // 1172 for 300k dst rows

    // ---- workspace ----
    const size_t PL = (size_t)(NA + NB) * 64;
    u16* plane[2];
    plane[0] = (u16*)d_ws;
    plane[1] = plane[0] + PL;
    u16* wh     = plane[1] + PL;                 // 11*4096
    u16* meanB  = wh + 11 * 4096;
    u16* meanA1 = meanB + (size_t)NB * 64;
    u16* meanA2 = meanA1 + (size_t)NA * 64;
    int* ghist  = (int*)(meanA2 + (size_t)NA * 64);   // KMAX
    int* bbase  = ghist + KMAX;                        // KMAX+1
    int* gcursor= bbase + KMAX + 1;                    // KMAX
    int* pairs  = gcursor + KMAX;                      // 3E (persists across layers)

    // ---- prep + bucket count ----
    int bA = (NA * 16 + 255) / 256, bB = (NB * 16 + 255) / 256;
    hipMemsetAsync(ghist, 0, KMAX * 4, stream);
    prep_count<<<bA + bB + 11 + 512, 256, 0, stream>>>(
        xA_in, xB_in, Wn, Wr, W_out, plane[0], wh,
        dst0, dst1, dst2, ghist, NA, NB, E, total, K);

    // ---- bucket bases + tile-staged partition (coalesced pairs writes) ----
    bucket_scan<<<1, 256, 0, stream>>>(ghist, bbase, gcursor, K, total);
    int ntiles = (total + TILE - 1) / TILE;
    partition_kernel<<<ntiles, 256, 0, stream>>>(src0, dst0, src1, dst1, src2, dst2,
                                                 gcursor, pairs, NB, NA, E, total);

    // ---- layers: edge-major aggregate (replaces bucket_fill + gather) ----
    const int blocksB = (NB + 63) / 64;
    const int blocksA = (NA + 63) / 64;
    int p = 0;
    for (int l = 0; l < 2; l++) {
        aggregate<<<K, 512, 0, stream>>>(plane[p], pairs, bbase,
                                         meanB, meanA1, meanA2, NB, NA, M);
        layer_kernel<<<blocksB + blocksA, 256, 0, stream>>>(
            plane[p], plane[1 - p], meanB, meanA1, meanA2, wh, b, l, NA, NB, blocksB);
        p = 1 - p;
    }

    // ---- head ----
    head_kernel<<<(NA + NB + 63) / 64, 256, 0, stream>>>(
        plane[p], wh, b_out, (float*)d_out, NA + NB);
}

// Round 4
// 455.992 us; speedup vs baseline: 6.3367x; 6.3367x over previous
//
#include <hip/hip_runtime.h>
#include <hip/hip_bf16.h>

typedef __bf16 bf16_t;
typedef unsigned short u16;
typedef short short8 __attribute__((ext_vector_type(8)));
typedef float f32x4 __attribute__((ext_vector_type(4)));

#define BSHIFT 9            // 512 dst-rows per bucket
#define TILE 8192

__device__ inline short f2bs(float v) {
    bf16_t h = (bf16_t)v;
    return __builtin_bit_cast(short, h);
}
__device__ inline float uif(unsigned u) { return __builtin_bit_cast(float, u); }

// ---------------- prep (cvt + weights) + bucket_count, one launch ----------------
// wh mats (transposed [n*64+k]): 0..5 Wn[l*3+e]; 6,7 WrB[l]=Wr[l,0];
// 8,9 WrA[l]=Wr[l,1]+Wr[l,2] (f32 pre-sum); 10 W_out.
__global__ __launch_bounds__(256) void prep_count(
    const float* __restrict__ xA, const float* __restrict__ xB,
    const float* __restrict__ Wn, const float* __restrict__ Wr,
    const float* __restrict__ Wout,
    u16* __restrict__ plane0, u16* __restrict__ wh,
    const int* __restrict__ d0, const int* __restrict__ d1,
    const int* __restrict__ d2, int* __restrict__ ghist,
    int NA, int NB, int E, int total, int K) {
    __shared__ int h[1024];
    int nA4 = NA * 16, nB4 = NB * 16;
    int bA = (nA4 + 255) / 256, bB = (nB4 + 255) / 256;
    int bi = blockIdx.x;
    int tid = threadIdx.x;
    if (bi < bA + bB) {
        const float* in = (bi < bA) ? xA : xB;
        u16* out = (bi < bA) ? plane0 : plane0 + (size_t)NA * 64;
        int i = (bi < bA ? bi : bi - bA) * 256 + tid;
        int n4 = (bi < bA) ? nA4 : nB4;
        if (i >= n4) return;
        float4 v = ((const float4*)in)[i];
        u16 o[4];
        o[0] = (u16)f2bs(v.x); o[1] = (u16)f2bs(v.y);
        o[2] = (u16)f2bs(v.z); o[3] = (u16)f2bs(v.w);
        *(uint2*)(out + (size_t)i * 4) = *(uint2*)o;
        return;
    }
    if (bi < bA + bB + 11) {
        int mat = bi - bA - bB;      // 0..10
        u16* dstp = wh + (size_t)mat * 4096;
        for (int i = tid; i < 4096; i += 256) {
            int k = i >> 6, n = i & 63;
            float v;
            if (mat < 6) v = Wn[(size_t)mat * 4096 + i];
            else if (mat < 8) v = Wr[(size_t)((mat - 6) * 3 + 0) * 4096 + i];
            else if (mat < 10) v = Wr[(size_t)((mat - 8) * 3 + 1) * 4096 + i]
                                 + Wr[(size_t)((mat - 8) * 3 + 2) * 4096 + i];
            else v = Wout[i];
            dstp[n * 64 + k] = (u16)f2bs(v);
        }
        return;
    }
    // ---- bucket_count portion (512 blocks, grid-stride, LDS hist) ----
    int cb = bi - (bA + bB + 11);
    for (int i = tid; i < 1024; i += 256) h[i] = 0;
    __syncthreads();
    for (int i = cb * 256 + tid; i < total; i += 512 * 256) {
        int g;
        if (i < E) g = d0[i];
        else if (i < 2 * E) g = NB + d1[i - E];
        else g = NB + NA + d2[i - 2 * E];
        atomicAdd(&h[g >> BSHIFT], 1);
    }
    __syncthreads();
    for (int i = tid; i < K; i += 256)
        if (h[i]) atomicAdd(&ghist[i], h[i]);
}

__global__ __launch_bounds__(256) void bucket_scan(const int* __restrict__ ghist,
                                                   int* __restrict__ bbase,
                                                   int* __restrict__ gcursor,
                                                   int K, int total) {
    __shared__ int ssum[256];
    int tid = threadIdx.x;
    int v[4]; int s = 0;
#pragma unroll
    for (int j = 0; j < 4; j++) {
        int i = tid * 4 + j;
        v[j] = s;
        s += (i < K) ? ghist[i] : 0;
    }
    ssum[tid] = s; __syncthreads();
    for (int off = 1; off < 256; off <<= 1) {
        int t = (tid >= off) ? ssum[tid - off] : 0; __syncthreads();
        ssum[tid] += t; __syncthreads();
    }
    int exc = tid ? ssum[tid - 1] : 0;
#pragma unroll
    for (int j = 0; j < 4; j++) {
        int i = tid * 4 + j;
        if (i < K) { bbase[i] = exc + v[j]; gcursor[i] = exc + v[j]; }
    }
    if (tid == 255) bbase[K] = total;
}

// pairs entry: packed = ((g & 511) << 17) | src   (src < 2^17, bucket = g >> 9)
__global__ __launch_bounds__(256) void partition_kernel(
    const int* __restrict__ s0, const int* __restrict__ d0,
    const int* __restrict__ s1, const int* __restrict__ d1,
    const int* __restrict__ s2, const int* __restrict__ d2,
    int* __restrict__ gcursor, int* __restrict__ pairs,
    int NB, int NA, int E, int total) {
    __shared__ int hist[1024];
    __shared__ int gbase[1024];
    __shared__ int ssum[256];
    __shared__ int2 buf[TILE];   // {packed, bkt}
    int tid = threadIdx.x;
    for (int tile = blockIdx.x * TILE; tile < total; tile += gridDim.x * TILE) {
        for (int i = tid; i < 1024; i += 256) hist[i] = 0;
        __syncthreads();
        int cnt = min(TILE, total - tile);
        int mybkt[32], mypk[32], myrank[32];
#pragma unroll
        for (int j = 0; j < 32; j++) {
            int idx = tile + j * 256 + tid;
            int g = -1, s = 0;
            if (idx < total) {
                if (idx < E) { s = s0[idx]; g = d0[idx]; }
                else if (idx < 2 * E) { s = s1[idx - E]; g = NB + d1[idx - E]; }
                else { s = s2[idx - 2 * E]; g = NB + NA + d2[idx - 2 * E]; }
            }
            if (g >= 0) {
                mybkt[j] = g >> BSHIFT;
                mypk[j] = ((g & ((1 << BSHIFT) - 1)) << 17) | s;
                myrank[j] = atomicAdd(&hist[mybkt[j]], 1);
            } else mybkt[j] = -1;
        }
        __syncthreads();
        int l[4]; int base4 = tid * 4; int ts = 0;
#pragma unroll
        for (int j = 0; j < 4; j++) { l[j] = hist[base4 + j]; ts += l[j]; }
        ssum[tid] = ts; __syncthreads();
        for (int off = 1; off < 256; off <<= 1) {
            int t = (tid >= off) ? ssum[tid - off] : 0; __syncthreads();
            ssum[tid] += t; __syncthreads();
        }
        int exc = tid ? ssum[tid - 1] : 0;
#pragma unroll
        for (int j = 0; j < 4; j++) {
            hist[base4 + j] = exc;
            if (l[j]) gbase[base4 + j] = atomicAdd(&gcursor[base4 + j], l[j]);
            exc += l[j];
        }
        __syncthreads();
#pragma unroll
        for (int j = 0; j < 32; j++) {
            if (mybkt[j] >= 0)
                buf[hist[mybkt[j]] + myrank[j]] = make_int2(mypk[j], mybkt[j]);
        }
        __syncthreads();
        for (int i = tid; i < cnt; i += 256) {
            int2 p = buf[i];
            pairs[gbase[p.y] + (i - hist[p.y])] = p.x;
        }
        __syncthreads();
    }
}

__global__ __launch_bounds__(256) void bucket_fill(const int* __restrict__ pairs,
                                                   const int* __restrict__ bbase,
                                                   int* __restrict__ off,
                                                   int* __restrict__ colidx,
                                                   int M, int K) {
    int b = blockIdx.x;
    int gb = b << BSHIFT;
    __shared__ int cnt[512], cur[512], ssum[256];
    int tid = threadIdx.x;
    int p0 = bbase[b], p1 = bbase[b + 1];
    for (int i = tid; i < 512; i += 256) cnt[i] = 0;
    __syncthreads();
    for (int e = p0 + tid; e < p1; e += 256)
        atomicAdd(&cnt[(unsigned)pairs[e] >> 17], 1);
    __syncthreads();
    int l0 = cnt[tid * 2], l1 = cnt[tid * 2 + 1];
    ssum[tid] = l0 + l1; __syncthreads();
    for (int o = 1; o < 256; o <<= 1) {
        int t = (tid >= o) ? ssum[tid - o] : 0; __syncthreads();
        ssum[tid] += t; __syncthreads();
    }
    int exc = tid ? ssum[tid - 1] : 0;
    cur[tid * 2] = exc;
    cur[tid * 2 + 1] = exc + l0;
    int g0 = gb + tid * 2, g1 = g0 + 1;
    if (g0 < M) off[g0] = p0 + exc;
    if (g1 < M) off[g1] = p0 + exc + l0;
    if (b == K - 1 && tid == 0) off[M] = p1;
    __syncthreads();
    for (int e = p0 + tid; e < p1; e += 256) {
        int p = pairs[e];
        int pos = atomicAdd(&cur[(unsigned)p >> 17], 1);
        colidx[p0 + pos] = p & 0x1FFFF;
    }
}

// ---------------- gather-mean: one row per 8-lane octet, dwordx4, 4-deep pipeline ----
// Each wave owns 8 consecutive dst rows (one per octet). A row is 64 bf16 =
// 128 B = 8 lanes x 16 B. Each lane accumulates its 8 features in registers;
// no cross-lane reduction. 4 row-loads + 4 colidx prefetches in flight per lane.
__device__ __forceinline__ void acc8(uint4 u, f32x4& a0, f32x4& a1) {
    a0[0] += uif(u.x << 16); a0[1] += uif(u.x & 0xFFFF0000u);
    a0[2] += uif(u.y << 16); a0[3] += uif(u.y & 0xFFFF0000u);
    a1[0] += uif(u.z << 16); a1[1] += uif(u.z & 0xFFFF0000u);
    a1[2] += uif(u.w << 16); a1[3] += uif(u.w & 0xFFFF0000u);
}

__global__ __launch_bounds__(256) void gather_all(const u16* __restrict__ plane,
                                                  const int* __restrict__ colidx,
                                                  const int* __restrict__ off,
                                                  u16* __restrict__ meanB,
                                                  u16* __restrict__ meanA1,
                                                  u16* __restrict__ meanA2,
                                                  int NB, int NA) {
    int wid = (blockIdx.x * 256 + threadIdx.x) >> 6;   // wave id
    int lane = threadIdx.x & 63;
    int oct = lane >> 3, fl = lane & 7;
    int M = NB + 2 * NA;
    int grow = wid * 8 + oct;
    if (grow >= M) return;

    const char* tab;
    u16* outp;
    int orow;
    if (grow < NB) { tab = (const char*)plane; outp = meanB; orow = grow; }
    else if (grow < NB + NA) { tab = (const char*)(plane + (size_t)NA * 64); outp = meanA1; orow = grow - NB; }
    else { tab = (const char*)plane; outp = meanA2; orow = grow - NB - NA; }

    int s0 = off[grow], s1 = off[grow + 1];
    unsigned fo = (unsigned)(fl << 4);                 // byte offset within row
    f32x4 a0 = {0.f, 0.f, 0.f, 0.f}, a1 = {0.f, 0.f, 0.f, 0.f};

    int e = s0;
    if (e + 3 < s1) {
        int c0 = colidx[e], c1 = colidx[e + 1];
        int c2 = colidx[e + 2], c3 = colidx[e + 3];
        while (e + 7 < s1) {
            uint4 u0 = *(const uint4*)(tab + (((unsigned)c0 << 7) | fo));
            uint4 u1 = *(const uint4*)(tab + (((unsigned)c1 << 7) | fo));
            uint4 u2 = *(const uint4*)(tab + (((unsigned)c2 << 7) | fo));
            uint4 u3 = *(const uint4*)(tab + (((unsigned)c3 << 7) | fo));
            c0 = colidx[e + 4]; c1 = colidx[e + 5];    // prefetch next quad
            c2 = colidx[e + 6]; c3 = colidx[e + 7];
            acc8(u0, a0, a1); acc8(u1, a0, a1);
            acc8(u2, a0, a1); acc8(u3, a0, a1);
            e += 4;
        }
        {   // drain the pipelined quad
            uint4 u0 = *(const uint4*)(tab + (((unsigned)c0 << 7) | fo));
            uint4 u1 = *(const uint4*)(tab + (((unsigned)c1 << 7) | fo));
            uint4 u2 = *(const uint4*)(tab + (((unsigned)c2 << 7) | fo));
            uint4 u3 = *(const uint4*)(tab + (((unsigned)c3 << 7) | fo));
            acc8(u0, a0, a1); acc8(u1, a0, a1);
            acc8(u2, a0, a1); acc8(u3, a0, a1);
            e += 4;
        }
    }
    for (; e < s1; ++e) {                              // up to 3 leftovers
        int c = colidx[e];
        uint4 u = *(const uint4*)(tab + (((unsigned)c << 7) | fo));
        acc8(u, a0, a1);
    }

    float inv = 1.0f / fmaxf((float)(s1 - s0), 1.0f);
    u16 o[8];
#pragma unroll
    for (int i = 0; i < 4; i++) o[i] = (u16)f2bs(a0[i] * inv);
#pragma unroll
    for (int i = 0; i < 4; i++) o[4 + i] = (u16)f2bs(a1[i] * inv);
    *(uint4*)(outp + (size_t)orow * 64 + fl * 8) = *(uint4*)o;
}

// ---------------- fused linear body (bf16 in, MFMA, bf16 or f32 out) ----------------
// A[m=lane&15][k=(lane>>4)*8+j], B[k][n=lane&15] (pre-transposed),
// C/D row=(lane>>4)*4+reg, col=lane&15.
template <int NM, int RELU, int OUTF32>
__device__ __forceinline__ void lin_body(
    const u16* __restrict__ m0, const u16* __restrict__ m1,
    const u16* __restrict__ x,
    const u16* __restrict__ Wm0t, const u16* __restrict__ Wm1t,
    const u16* __restrict__ Wxt,
    const float* __restrict__ bias0, const float* __restrict__ bias1,
    void* __restrict__ outv, int nrows, int blk) {
    const int lane = threadIdx.x & 63;
    const int wave = threadIdx.x >> 6;
    const int row0 = blk * 64 + wave * 16;
    if (row0 >= nrows) return;
    const int r = lane & 15;
    const int q = lane >> 4;

    short8 wm0f[2][4], wm1f[2][4], wxf[2][4];
#pragma unroll
    for (int ks = 0; ks < 2; ks++) {
#pragma unroll
        for (int t = 0; t < 4; t++) {
            size_t widx = (size_t)(t * 16 + r) * 64 + ks * 32 + q * 8;
            if (NM >= 1) wm0f[ks][t] = *(const short8*)(Wm0t + widx);
            if (NM >= 2) wm1f[ks][t] = *(const short8*)(Wm1t + widx);
            wxf[ks][t] = *(const short8*)(Wxt + widx);
        }
    }

    f32x4 acc[4];
#pragma unroll
    for (int t = 0; t < 4; t++) {
        float bv = bias0[t * 16 + r];
        if (bias1) bv += bias1[t * 16 + r];
        acc[t][0] = bv; acc[t][1] = bv; acc[t][2] = bv; acc[t][3] = bv;
    }

    const int arow = row0 + r;
    const bool avalid = arow < nrows;
    short8 zf;
#pragma unroll
    for (int j = 0; j < 8; j++) zf[j] = 0;

    if (NM >= 1) {
#pragma unroll
        for (int ks = 0; ks < 2; ks++) {
            short8 af = avalid ? *(const short8*)(m0 + (size_t)arow * 64 + ks * 32 + q * 8) : zf;
#pragma unroll
            for (int t = 0; t < 4; t++)
                acc[t] = __builtin_amdgcn_mfma_f32_16x16x32_bf16(af, wm0f[ks][t], acc[t], 0, 0, 0);
        }
    }
    if (NM >= 2) {
#pragma unroll
        for (int ks = 0; ks < 2; ks++) {
            short8 af = avalid ? *(const short8*)(m1 + (size_t)arow * 64 + ks * 32 + q * 8) : zf;
#pragma unroll
            for (int t = 0; t < 4; t++)
                acc[t] = __builtin_amdgcn_mfma_f32_16x16x32_bf16(af, wm1f[ks][t], acc[t], 0, 0, 0);
        }
    }
#pragma unroll
    for (int ks = 0; ks < 2; ks++) {
        short8 xf = avalid ? *(const short8*)(x + (size_t)arow * 64 + ks * 32 + q * 8) : zf;
#pragma unroll
        for (int t = 0; t < 4; t++)
            acc[t] = __builtin_amdgcn_mfma_f32_16x16x32_bf16(xf, wxf[ks][t], acc[t], 0, 0, 0);
    }

#pragma unroll
    for (int t = 0; t < 4; t++) {
#pragma unroll
        for (int rr = 0; rr < 4; rr++) {
            int row = row0 + q * 4 + rr;
            if (row < nrows) {
                float v = acc[t][rr];
                if (RELU) v = fmaxf(v, 0.0f);
                if (OUTF32) ((float*)outv)[(size_t)row * 64 + t * 16 + r] = v;
                else ((u16*)outv)[(size_t)row * 64 + t * 16 + r] = (u16)f2bs(v);
            }
        }
    }
}

// one layer: B-phase blocks [0,blocksB), A-phase blocks [blocksB, ...)
__global__ __launch_bounds__(256) void layer_kernel(
    const u16* __restrict__ plane_in, u16* __restrict__ plane_out,
    const u16* __restrict__ meanB, const u16* __restrict__ meanA1,
    const u16* __restrict__ meanA2, const u16* __restrict__ wh,
    const float* __restrict__ bvec, int l, int NA, int NB, int blocksB) {
    if ((int)blockIdx.x < blocksB) {
        // new_B = mean(A->B)@Wn[l,0] + x_B@Wr[l,0] + b[l,0]
        lin_body<1, 0, 0>(meanB, nullptr, plane_in + (size_t)NA * 64,
                          wh + (size_t)(l * 3 + 0) * 4096, nullptr,
                          wh + (size_t)(6 + l) * 4096,
                          bvec + (size_t)(l * 3 + 0) * 64, nullptr,
                          plane_out + (size_t)NA * 64, NB, blockIdx.x);
    } else {
        // new_A = mean(B->A)@Wn[l,1] + mean(A->A)@Wn[l,2] + x_A@(Wr[l,1]+Wr[l,2]) + b[l,1]+b[l,2]
        lin_body<2, 0, 0>(meanA1, meanA2, plane_in,
                          wh + (size_t)(l * 3 + 1) * 4096, wh + (size_t)(l * 3 + 2) * 4096,
                          wh + (size_t)(8 + l) * 4096,
                          bvec + (size_t)(l * 3 + 1) * 64, bvec + (size_t)(l * 3 + 2) * 64,
                          plane_out, NA, blockIdx.x - blocksB);
    }
}

// head over NA+NB contiguous rows
__global__ __launch_bounds__(256) void head_kernel(
    const u16* __restrict__ plane_in, const u16* __restrict__ wh,
    const float* __restrict__ b_out, float* __restrict__ out, int nrows) {
    lin_body<0, 1, 1>(nullptr, nullptr, plane_in,
                      nullptr, nullptr, wh + (size_t)10 * 4096,
                      b_out, nullptr, out, nrows, blockIdx.x);
}

// ---------------- launch ----------------
extern "C" void kernel_launch(void* const* d_in, const int* in_sizes, int n_in,
                              void* d_out, int out_size, void* d_ws, size_t ws_size,
                              hipStream_t stream) {
    const float* xA_in = (const float*)d_in[0];
    const float* xB_in = (const float*)d_in[1];
    const float* Wn = (const float*)d_in[2];
    const float* Wr = (const float*)d_in[3];
    const float* b = (const float*)d_in[4];
    const float* W_out = (const float*)d_in[5];
    const float* b_out = (const float*)d_in[6];
    const int* src0 = (const int*)d_in[7];
    const int* dst0 = (const int*)d_in[8];
    const int* src1 = (const int*)d_in[9];
    const int* dst1 = (const int*)d_in[10];
    const int* src2 = (const int*)d_in[11];
    const int* dst2 = (const int*)d_in[12];

    const int NA = in_sizes[0] / 64;
    const int NB = in_sizes[1] / 64;
    const int E = in_sizes[7];
    const int M = NB + NA + NA;
    const int total = 3 * E;
    const int K = (M + (1 << BSHIFT) - 1) >> BSHIFT;   // 586 for 300k dst rows

    // ---- workspace ----
    const size_t PL = (size_t)(NA + NB) * 64;
    u16* plane[2];
    plane[0] = (u16*)d_ws;
    plane[1] = plane[0] + PL;
    u16* wh     = plane[1] + PL;                 // 11*4096
    u16* meanB  = wh + 11 * 4096;
    u16* meanA1 = meanB + (size_t)NB * 64;
    u16* meanA2 = meanA1 + (size_t)NA * 64;
    int* ghist  = (int*)(meanA2 + (size_t)NA * 64);
    int* bbase  = ghist + 1024;
    int* gcursor= bbase + 1025;
    int* off    = gcursor + 1024;
    int* colidx = off + (M + 1);
    int* pairs  = (int*)meanB;   // aliases means region (dead until gathers run)

    // ---- prep + count ----
    int bA = (NA * 16 + 255) / 256, bB = (NB * 16 + 255) / 256;
    hipMemsetAsync(ghist, 0, 1024 * 4, stream);
    prep_count<<<bA + bB + 11 + 512, 256, 0, stream>>>(
        xA_in, xB_in, Wn, Wr, W_out, plane[0], wh,
        dst0, dst1, dst2, ghist, NA, NB, E, total, K);

    // ---- CSR build ----
    bucket_scan<<<1, 256, 0, stream>>>(ghist, bbase, gcursor, K, total);
    int ntiles = (total + TILE - 1) / TILE;
    partition_kernel<<<ntiles, 256, 0, stream>>>(src0, dst0, src1, dst1, src2, dst2,
                                                 gcursor, pairs, NB, NA, E, total);
    bucket_fill<<<K, 256, 0, stream>>>(pairs, bbase, off, colidx, M, K);

    // ---- layers ----
    const int blocksB = (NB + 63) / 64;
    const int blocksA = (NA + 63) / 64;
    int p = 0;
    for (int l = 0; l < 2; l++) {
        gather_all<<<(M + 31) / 32, 256, 0, stream>>>(plane[p], colidx, off,
                                                      meanB, meanA1, meanA2, NB, NA);
        layer_kernel<<<blocksB + blocksA, 256, 0, stream>>>(
            plane[p], plane[1 - p], meanB, meanA1, meanA2, wh, b, l, NA, NB, blocksB);
        p = 1 - p;
    }

    // ---- head ----
    head_kernel<<<(NA + NB + 63) / 64, 256, 0, stream>>>(
        plane[p], wh, b_out, (float*)d_out, NA + NB);
}

// Round 5
// 453.128 us; speedup vs baseline: 6.3768x; 1.0063x over previous
//
#include <hip/hip_runtime.h>
#include <hip/hip_bf16.h>

typedef __bf16 bf16_t;
typedef unsigned short u16;
typedef short short8 __attribute__((ext_vector_type(8)));
typedef float f32x4 __attribute__((ext_vector_type(4)));

#define BSHIFT 9            // 512 dst-rows per bucket
#define CAP 8192            // fixed slots per bucket (expected 6144 +- 78; 26 sigma)
#define TILE 8192

__device__ inline short f2bs(float v) {
    bf16_t h = (bf16_t)v;
    return __builtin_bit_cast(short, h);
}
__device__ inline float uif(unsigned u) { return __builtin_bit_cast(float, u); }

// ---------------- prep: f32->bf16 plane convert + weight transpose (no counting) ----------------
// wh mats (transposed [n*64+k]): 0..5 Wn[l*3+e]; 6,7 WrB[l]=Wr[l,0];
// 8,9 WrA[l]=Wr[l,1]+Wr[l,2] (f32 pre-sum); 10 W_out.
__global__ __launch_bounds__(256) void prep_convert(
    const float* __restrict__ xA, const float* __restrict__ xB,
    const float* __restrict__ Wn, const float* __restrict__ Wr,
    const float* __restrict__ Wout,
    u16* __restrict__ plane0, u16* __restrict__ wh, int NA, int NB) {
    int nA4 = NA * 16, nB4 = NB * 16;
    int bA = (nA4 + 255) / 256, bB = (nB4 + 255) / 256;
    int bi = blockIdx.x;
    int tid = threadIdx.x;
    if (bi < bA + bB) {
        const float* in = (bi < bA) ? xA : xB;
        u16* out = (bi < bA) ? plane0 : plane0 + (size_t)NA * 64;
        int i = (bi < bA ? bi : bi - bA) * 256 + tid;
        int n4 = (bi < bA) ? nA4 : nB4;
        if (i >= n4) return;
        float4 v = ((const float4*)in)[i];
        u16 o[4];
        o[0] = (u16)f2bs(v.x); o[1] = (u16)f2bs(v.y);
        o[2] = (u16)f2bs(v.z); o[3] = (u16)f2bs(v.w);
        *(uint2*)(out + (size_t)i * 4) = *(uint2*)o;
        return;
    }
    int mat = bi - bA - bB;      // 0..10
    u16* dstp = wh + (size_t)mat * 4096;
    for (int i = tid; i < 4096; i += 256) {
        int k = i >> 6, n = i & 63;
        float v;
        if (mat < 6) v = Wn[(size_t)mat * 4096 + i];
        else if (mat < 8) v = Wr[(size_t)((mat - 6) * 3 + 0) * 4096 + i];
        else if (mat < 10) v = Wr[(size_t)((mat - 8) * 3 + 1) * 4096 + i]
                             + Wr[(size_t)((mat - 8) * 3 + 2) * 4096 + i];
        else v = Wout[i];
        dstp[n * 64 + k] = (u16)f2bs(v);
    }
}

__global__ __launch_bounds__(256) void init_cursor(int* __restrict__ gcursor, int K) {
    int i = blockIdx.x * 256 + threadIdx.x;
    if (i < K) gcursor[i] = i * CAP;
}

// pairs entry: packed = ((g & 511) << 17) | src   (src < 2^17, bucket = g >> 9)
// bucket b's region is [b*CAP, b*CAP + cnt_b) -- fixed capacity, no pre-count needed.
__global__ __launch_bounds__(256) void partition_kernel(
    const int* __restrict__ s0, const int* __restrict__ d0,
    const int* __restrict__ s1, const int* __restrict__ d1,
    const int* __restrict__ s2, const int* __restrict__ d2,
    int* __restrict__ gcursor, int* __restrict__ pairs,
    int NB, int NA, int E, int total) {
    __shared__ int hist[1024];
    __shared__ int gbase[1024];
    __shared__ int ssum[256];
    __shared__ int2 buf[TILE];   // {packed, bkt}
    int tid = threadIdx.x;
    for (int tile = blockIdx.x * TILE; tile < total; tile += gridDim.x * TILE) {
        for (int i = tid; i < 1024; i += 256) hist[i] = 0;
        __syncthreads();
        int cnt = min(TILE, total - tile);
        int mybkt[32], mypk[32], myrank[32];
#pragma unroll
        for (int j = 0; j < 32; j++) {
            int idx = tile + j * 256 + tid;
            int g = -1, s = 0;
            if (idx < total) {
                if (idx < E) { s = s0[idx]; g = d0[idx]; }
                else if (idx < 2 * E) { s = s1[idx - E]; g = NB + d1[idx - E]; }
                else { s = s2[idx - 2 * E]; g = NB + NA + d2[idx - 2 * E]; }
            }
            if (g >= 0) {
                mybkt[j] = g >> BSHIFT;
                mypk[j] = ((g & ((1 << BSHIFT) - 1)) << 17) | s;
                myrank[j] = atomicAdd(&hist[mybkt[j]], 1);
            } else mybkt[j] = -1;
        }
        __syncthreads();
        int l[4]; int base4 = tid * 4; int ts = 0;
#pragma unroll
        for (int j = 0; j < 4; j++) { l[j] = hist[base4 + j]; ts += l[j]; }
        ssum[tid] = ts; __syncthreads();
        for (int off = 1; off < 256; off <<= 1) {
            int t = (tid >= off) ? ssum[tid - off] : 0; __syncthreads();
            ssum[tid] += t; __syncthreads();
        }
        int exc = tid ? ssum[tid - 1] : 0;
#pragma unroll
        for (int j = 0; j < 4; j++) {
            hist[base4 + j] = exc;
            if (l[j]) gbase[base4 + j] = atomicAdd(&gcursor[base4 + j], l[j]);
            exc += l[j];
        }
        __syncthreads();
#pragma unroll
        for (int j = 0; j < 32; j++) {
            if (mybkt[j] >= 0)
                buf[hist[mybkt[j]] + myrank[j]] = make_int2(mypk[j], mybkt[j]);
        }
        __syncthreads();
        for (int i = tid; i < cnt; i += 256) {
            int2 p = buf[i];
            pairs[gbase[p.y] + (i - hist[p.y])] = p.x;
        }
        __syncthreads();
    }
}

// bucket b: order pairs into colidx segments; emit per-row [off_s, off_e).
__global__ __launch_bounds__(256) void bucket_fill(const int* __restrict__ pairs,
                                                   const int* __restrict__ gcursor,
                                                   int* __restrict__ off_s,
                                                   int* __restrict__ off_e,
                                                   int* __restrict__ colidx, int M) {
    int b = blockIdx.x;
    int gb = b << BSHIFT;
    __shared__ int cnt[512], cur[512], ssum[256];
    int tid = threadIdx.x;
    int p0 = b * CAP, p1 = gcursor[b];
    for (int i = tid; i < 512; i += 256) cnt[i] = 0;
    __syncthreads();
    for (int e = p0 + tid; e < p1; e += 256)
        atomicAdd(&cnt[(unsigned)pairs[e] >> 17], 1);
    __syncthreads();
    int l0 = cnt[tid * 2], l1 = cnt[tid * 2 + 1];
    ssum[tid] = l0 + l1; __syncthreads();
    for (int o = 1; o < 256; o <<= 1) {
        int t = (tid >= o) ? ssum[tid - o] : 0; __syncthreads();
        ssum[tid] += t; __syncthreads();
    }
    int exc = tid ? ssum[tid - 1] : 0;
    cur[tid * 2] = exc;
    cur[tid * 2 + 1] = exc + l0;
    int g0 = gb + tid * 2, g1 = g0 + 1;
    if (g0 < M) { off_s[g0] = p0 + exc;      off_e[g0] = p0 + exc + l0; }
    if (g1 < M) { off_s[g1] = p0 + exc + l0; off_e[g1] = p0 + exc + l0 + l1; }
    __syncthreads();
    for (int e = p0 + tid; e < p1; e += 256) {
        int p = pairs[e];
        int pos = atomicAdd(&cur[(unsigned)p >> 17], 1);
        colidx[p0 + pos] = p & 0x1FFFF;
    }
}

// ---------------- fused gather+linear layer ----------------
// Wave owns 16 dst rows. Lane (q=lane>>4, r=lane&15) gathers row row0+r,
// byte chunks [q*16,q*16+16) and [64+q*16, ...): exactly the k-ranges
// ks*32+q*8 of the mfma_16x16x32 A-fragment. Mean goes straight into an
// MFMA A-frag; no mean arrays materialize.
__device__ __forceinline__ void acc8(uint4 u, f32x4& a0, f32x4& a1) {
    a0[0] += uif(u.x << 16); a0[1] += uif(u.x & 0xFFFF0000u);
    a0[2] += uif(u.y << 16); a0[3] += uif(u.y & 0xFFFF0000u);
    a1[0] += uif(u.z << 16); a1[1] += uif(u.z & 0xFFFF0000u);
    a1[2] += uif(u.w << 16); a1[3] += uif(u.w & 0xFFFF0000u);
}

__device__ __forceinline__ void gseg(const char* __restrict__ tab,
                                     const int* __restrict__ colidx,
                                     int s0, int s1, unsigned fo0,
                                     f32x4& a0, f32x4& a1, f32x4& a2, f32x4& a3) {
    unsigned fo1 = fo0 + 64;
    int e = s0;
    if (e + 1 < s1) {
        int c0 = colidx[e], c1 = colidx[e + 1];
        while (e + 3 < s1) {
            const char* r0 = tab + ((unsigned)c0 << 7);
            const char* r1 = tab + ((unsigned)c1 << 7);
            uint4 u0a = *(const uint4*)(r0 + fo0);
            uint4 u0b = *(const uint4*)(r0 + fo1);
            uint4 u1a = *(const uint4*)(r1 + fo0);
            uint4 u1b = *(const uint4*)(r1 + fo1);
            c0 = colidx[e + 2]; c1 = colidx[e + 3];    // prefetch next pair
            acc8(u0a, a0, a1); acc8(u0b, a2, a3);
            acc8(u1a, a0, a1); acc8(u1b, a2, a3);
            e += 2;
        }
        {   // drain (e+1 < s1 guaranteed by pipeline invariant)
            const char* r0 = tab + ((unsigned)c0 << 7);
            const char* r1 = tab + ((unsigned)c1 << 7);
            uint4 u0a = *(const uint4*)(r0 + fo0);
            uint4 u0b = *(const uint4*)(r0 + fo1);
            uint4 u1a = *(const uint4*)(r1 + fo0);
            uint4 u1b = *(const uint4*)(r1 + fo1);
            acc8(u0a, a0, a1); acc8(u0b, a2, a3);
            acc8(u1a, a0, a1); acc8(u1b, a2, a3);
            e += 2;
        }
    }
    if (e < s1) {                                      // odd leftover
        const char* r0 = tab + ((unsigned)colidx[e] << 7);
        uint4 ua = *(const uint4*)(r0 + fo0);
        uint4 ub = *(const uint4*)(r0 + fo1);
        acc8(ua, a0, a1); acc8(ub, a2, a3);
    }
}

__device__ __forceinline__ void mk_frag(const f32x4& a0, const f32x4& a1,
                                        const f32x4& a2, const f32x4& a3,
                                        float inv, short8& f0, short8& f1) {
#pragma unroll
    for (int j = 0; j < 4; j++) {
        f0[j]     = f2bs(a0[j] * inv);
        f0[4 + j] = f2bs(a1[j] * inv);
        f1[j]     = f2bs(a2[j] * inv);
        f1[4 + j] = f2bs(a3[j] * inv);
    }
}

template <int NM>
__device__ __forceinline__ void fused_body(
    const int* __restrict__ colidx,
    const int* __restrict__ off_s, const int* __restrict__ off_e,
    const u16* __restrict__ Wm0t, const u16* __restrict__ Wm1t,
    const u16* __restrict__ Wxt,
    const float* __restrict__ bias0, const float* __restrict__ bias1,
    const u16* __restrict__ xsrc,          // dense x rows
    const char* __restrict__ tab0,         // mean0 source table
    const char* __restrict__ tab1,         // mean1 source table (NM==2)
    int seg0, int seg1,                    // CSR segment-index bases
    u16* __restrict__ outp, int nrows, int blk) {
    const int lane = threadIdx.x & 63;
    const int wave = threadIdx.x >> 6;
    const int row0 = blk * 64 + wave * 16;
    if (row0 >= nrows) return;
    const int r = lane & 15;
    const int q = lane >> 4;
    const int arow = row0 + r;
    const bool avalid = arow < nrows;
    const unsigned fo0 = (unsigned)(q << 4);

    // gather mean0 -> frags
    f32x4 a0 = {0,0,0,0}, a1 = {0,0,0,0}, a2 = {0,0,0,0}, a3 = {0,0,0,0};
    int s0 = 0, s1 = 0;
    if (avalid) { int g = seg0 + arow; s0 = off_s[g]; s1 = off_e[g]; }
    gseg(tab0, colidx, s0, s1, fo0, a0, a1, a2, a3);
    float inv0 = 1.0f / fmaxf((float)(s1 - s0), 1.0f);
    short8 m0f0, m0f1;
    mk_frag(a0, a1, a2, a3, inv0, m0f0, m0f1);

    short8 m1f0, m1f1;
    if (NM >= 2) {
        a0 = {0,0,0,0}; a1 = {0,0,0,0}; a2 = {0,0,0,0}; a3 = {0,0,0,0};
        int t0 = 0, t1 = 0;
        if (avalid) { int g = seg1 + arow; t0 = off_s[g]; t1 = off_e[g]; }
        gseg(tab1, colidx, t0, t1, fo0, a0, a1, a2, a3);
        float inv1 = 1.0f / fmaxf((float)(t1 - t0), 1.0f);
        mk_frag(a0, a1, a2, a3, inv1, m1f0, m1f1);
    }

    // x-term frags (dense bf16 rows)
    short8 zf;
#pragma unroll
    for (int j = 0; j < 8; j++) zf[j] = 0;
    short8 xf0 = avalid ? *(const short8*)(xsrc + (size_t)arow * 64 + q * 8) : zf;
    short8 xf1 = avalid ? *(const short8*)(xsrc + (size_t)arow * 64 + 32 + q * 8) : zf;

    // accumulator with bias
    f32x4 acc[4];
#pragma unroll
    for (int t = 0; t < 4; t++) {
        float bv = bias0[t * 16 + r];
        if (NM >= 2) bv += bias1[t * 16 + r];
        acc[t][0] = bv; acc[t][1] = bv; acc[t][2] = bv; acc[t][3] = bv;
    }

    // MFMA: weight frags B[k][n] pre-transposed at [n*64+k]
#pragma unroll
    for (int ks = 0; ks < 2; ks++) {
        short8 mm0 = ks ? m0f1 : m0f0;
        short8 xx  = ks ? xf1 : xf0;
#pragma unroll
        for (int t = 0; t < 4; t++) {
            size_t widx = (size_t)(t * 16 + r) * 64 + ks * 32 + q * 8;
            short8 wm0 = *(const short8*)(Wm0t + widx);
            acc[t] = __builtin_amdgcn_mfma_f32_16x16x32_bf16(mm0, wm0, acc[t], 0, 0, 0);
            if (NM >= 2) {
                short8 wm1 = *(const short8*)(Wm1t + widx);
                short8 mm1 = ks ? m1f1 : m1f0;
                acc[t] = __builtin_amdgcn_mfma_f32_16x16x32_bf16(mm1, wm1, acc[t], 0, 0, 0);
            }
            short8 wx = *(const short8*)(Wxt + widx);
            acc[t] = __builtin_amdgcn_mfma_f32_16x16x32_bf16(xx, wx, acc[t], 0, 0, 0);
        }
    }

    // writeout: C/D row=(lane>>4)*4+reg, col=lane&15
#pragma unroll
    for (int t = 0; t < 4; t++) {
#pragma unroll
        for (int rr = 0; rr < 4; rr++) {
            int row = row0 + q * 4 + rr;
            if (row < nrows)
                outp[(size_t)row * 64 + t * 16 + r] = (u16)f2bs(acc[t][rr]);
        }
    }
}

// one layer: B-phase blocks [0,blocksB), A-phase blocks [blocksB, ...)
__global__ __launch_bounds__(256) void fused_layer(
    const u16* __restrict__ plane_in, u16* __restrict__ plane_out,
    const int* __restrict__ colidx,
    const int* __restrict__ off_s, const int* __restrict__ off_e,
    const u16* __restrict__ wh, const float* __restrict__ bvec,
    int l, int NA, int NB, int blocksB) {
    const u16* pA = plane_in;
    const u16* pB = plane_in + (size_t)NA * 64;
    if ((int)blockIdx.x < blocksB) {
        // new_B = mean(A->B)@Wn[l,0] + x_B@Wr[l,0] + b[l,0]
        fused_body<1>(colidx, off_s, off_e,
                      wh + (size_t)(l * 3 + 0) * 4096, nullptr,
                      wh + (size_t)(6 + l) * 4096,
                      bvec + (size_t)(l * 3 + 0) * 64, nullptr,
                      pB, (const char*)pA, nullptr,
                      0, 0,
                      plane_out + (size_t)NA * 64, NB, blockIdx.x);
    } else {
        // new_A = mean(B->A)@Wn[l,1] + mean(A->A)@Wn[l,2] + x_A@(Wr[l,1]+Wr[l,2]) + b[l,1]+b[l,2]
        fused_body<2>(colidx, off_s, off_e,
                      wh + (size_t)(l * 3 + 1) * 4096, wh + (size_t)(l * 3 + 2) * 4096,
                      wh + (size_t)(8 + l) * 4096,
                      bvec + (size_t)(l * 3 + 1) * 64, bvec + (size_t)(l * 3 + 2) * 64,
                      pA, (const char*)pB, (const char*)pA,
                      NB, NB + NA,
                      plane_out, NA, blockIdx.x - blocksB);
    }
}

// ---------------- head (dense Linear+ReLU, f32 out) ----------------
// A[m=lane&15][k=(lane>>4)*8+j], B[k][n=lane&15] (pre-transposed),
// C/D row=(lane>>4)*4+reg, col=lane&15.
__global__ __launch_bounds__(256) void head_kernel(
    const u16* __restrict__ plane_in, const u16* __restrict__ wh,
    const float* __restrict__ b_out, float* __restrict__ out, int nrows) {
    const int lane = threadIdx.x & 63;
    const int wave = threadIdx.x >> 6;
    const int row0 = blockIdx.x * 64 + wave * 16;
    if (row0 >= nrows) return;
    const int r = lane & 15;
    const int q = lane >> 4;
    const u16* Wxt = wh + (size_t)10 * 4096;

    f32x4 acc[4];
#pragma unroll
    for (int t = 0; t < 4; t++) {
        float bv = b_out[t * 16 + r];
        acc[t][0] = bv; acc[t][1] = bv; acc[t][2] = bv; acc[t][3] = bv;
    }

    const int arow = row0 + r;
    const bool avalid = arow < nrows;
    short8 zf;
#pragma unroll
    for (int j = 0; j < 8; j++) zf[j] = 0;

#pragma unroll
    for (int ks = 0; ks < 2; ks++) {
        short8 xf = avalid ? *(const short8*)(plane_in + (size_t)arow * 64 + ks * 32 + q * 8) : zf;
#pragma unroll
        for (int t = 0; t < 4; t++) {
            short8 wx = *(const short8*)(Wxt + (size_t)(t * 16 + r) * 64 + ks * 32 + q * 8);
            acc[t] = __builtin_amdgcn_mfma_f32_16x16x32_bf16(xf, wx, acc[t], 0, 0, 0);
        }
    }

#pragma unroll
    for (int t = 0; t < 4; t++) {
#pragma unroll
        for (int rr = 0; rr < 4; rr++) {
            int row = row0 + q * 4 + rr;
            if (row < nrows)
                out[(size_t)row * 64 + t * 16 + r] = fmaxf(acc[t][rr], 0.0f);
        }
    }
}

// ---------------- launch ----------------
extern "C" void kernel_launch(void* const* d_in, const int* in_sizes, int n_in,
                              void* d_out, int out_size, void* d_ws, size_t ws_size,
                              hipStream_t stream) {
    const float* xA_in = (const float*)d_in[0];
    const float* xB_in = (const float*)d_in[1];
    const float* Wn = (const float*)d_in[2];
    const float* Wr = (const float*)d_in[3];
    const float* b = (const float*)d_in[4];
    const float* W_out = (const float*)d_in[5];
    const float* b_out = (const float*)d_in[6];
    const int* src0 = (const int*)d_in[7];
    const int* dst0 = (const int*)d_in[8];
    const int* src1 = (const int*)d_in[9];
    const int* dst1 = (const int*)d_in[10];
    const int* src2 = (const int*)d_in[11];
    const int* dst2 = (const int*)d_in[12];

    const int NA = in_sizes[0] / 64;
    const int NB = in_sizes[1] / 64;
    const int E = in_sizes[7];
    const int M = NB + NA + NA;
    const int total = 3 * E;
    const int K = (M + (1 << BSHIFT) - 1) >> BSHIFT;   // 586 for 300k dst rows

    // ---- workspace ----
    const size_t PL = (size_t)(NA + NB) * 64;
    u16* plane[2];
    plane[0] = (u16*)d_ws;
    plane[1] = plane[0] + PL;
    u16* wh     = plane[1] + PL;                 // 11*4096
    int* gcursor= (int*)(wh + 11 * 4096);        // K (alloc 1024)
    int* off_s  = gcursor + 1024;                // M
    int* off_e  = off_s + M;                     // M
    int* colidx = off_e + M;                     // K*CAP (bucket-padded)
    int* pairs  = colidx + (size_t)K * CAP;      // K*CAP

    // ---- prep (convert + weights) ----
    int bA = (NA * 16 + 255) / 256, bB = (NB * 16 + 255) / 256;
    prep_convert<<<bA + bB + 11, 256, 0, stream>>>(
        xA_in, xB_in, Wn, Wr, W_out, plane[0], wh, NA, NB);

    // ---- CSR build: fixed-capacity buckets, no counting pass ----
    init_cursor<<<(K + 255) / 256, 256, 0, stream>>>(gcursor, K);
    int ntiles = (total + TILE - 1) / TILE;
    partition_kernel<<<ntiles, 256, 0, stream>>>(src0, dst0, src1, dst1, src2, dst2,
                                                 gcursor, pairs, NB, NA, E, total);
    bucket_fill<<<K, 256, 0, stream>>>(pairs, gcursor, off_s, off_e, colidx, M);

    // ---- layers: fused gather+MFMA (no mean arrays) ----
    const int blocksB = (NB + 63) / 64;
    const int blocksA = (NA + 63) / 64;
    int p = 0;
    for (int l = 0; l < 2; l++) {
        fused_layer<<<blocksB + blocksA, 256, 0, stream>>>(
            plane[p], plane[1 - p], colidx, off_s, off_e, wh, b, l, NA, NB, blocksB);
        p = 1 - p;
    }

    // ---- head ----
    head_kernel<<<(NA + NB + 63) / 64, 256, 0, stream>>>(
        plane[p], wh, b_out, (float*)d_out, NA + NB);
}

// Round 6
// 440.292 us; speedup vs baseline: 6.5627x; 1.0292x over previous
//
#include <hip/hip_runtime.h>
#include <hip/hip_bf16.h>

typedef __bf16 bf16_t;
typedef unsigned short u16;
typedef short short8 __attribute__((ext_vector_type(8)));
typedef float f32x4 __attribute__((ext_vector_type(4)));

#define BSHIFT 9            // 512 dst-rows per bucket
#define CAP 8192            // fixed slots per bucket (expected 6144 +- 78; 26 sigma)
#define TILE 8192

__device__ inline short f2bs(float v) {
    bf16_t h = (bf16_t)v;
    return __builtin_bit_cast(short, h);
}
__device__ inline float uif(unsigned u) { return __builtin_bit_cast(float, u); }

// ---------------- prep: f32->bf16 plane convert + weight transpose ----------------
// wh mats (transposed [n*64+k]): 0..5 Wn[l*3+e]; 6,7 WrB[l]=Wr[l,0];
// 8,9 WrA[l]=Wr[l,1]+Wr[l,2] (f32 pre-sum); 10 W_out.
__global__ __launch_bounds__(256) void prep_convert(
    const float* __restrict__ xA, const float* __restrict__ xB,
    const float* __restrict__ Wn, const float* __restrict__ Wr,
    const float* __restrict__ Wout,
    u16* __restrict__ plane0, u16* __restrict__ wh, int NA, int NB) {
    int nA4 = NA * 16, nB4 = NB * 16;
    int bA = (nA4 + 255) / 256, bB = (nB4 + 255) / 256;
    int bi = blockIdx.x;
    int tid = threadIdx.x;
    if (bi < bA + bB) {
        const float* in = (bi < bA) ? xA : xB;
        u16* out = (bi < bA) ? plane0 : plane0 + (size_t)NA * 64;
        int i = (bi < bA ? bi : bi - bA) * 256 + tid;
        int n4 = (bi < bA) ? nA4 : nB4;
        if (i >= n4) return;
        float4 v = ((const float4*)in)[i];
        u16 o[4];
        o[0] = (u16)f2bs(v.x); o[1] = (u16)f2bs(v.y);
        o[2] = (u16)f2bs(v.z); o[3] = (u16)f2bs(v.w);
        *(uint2*)(out + (size_t)i * 4) = *(uint2*)o;
        return;
    }
    int mat = bi - bA - bB;      // 0..10
    u16* dstp = wh + (size_t)mat * 4096;
    for (int i = tid; i < 4096; i += 256) {
        int k = i >> 6, n = i & 63;
        float v;
        if (mat < 6) v = Wn[(size_t)mat * 4096 + i];
        else if (mat < 8) v = Wr[(size_t)((mat - 6) * 3 + 0) * 4096 + i];
        else if (mat < 10) v = Wr[(size_t)((mat - 8) * 3 + 1) * 4096 + i]
                             + Wr[(size_t)((mat - 8) * 3 + 2) * 4096 + i];
        else v = Wout[i];
        dstp[n * 64 + k] = (u16)f2bs(v);
    }
}

__global__ __launch_bounds__(256) void init_cursor(int* __restrict__ gcursor, int K) {
    int i = blockIdx.x * 256 + threadIdx.x;
    if (i < K) gcursor[i] = i * CAP;
}

// pairs entry: packed = ((g & 511) << 17) | src   (src < 2^17, bucket = g >> 9)
// bucket b's region is [b*CAP, b*CAP + cnt_b) -- fixed capacity, no pre-count needed.
__global__ __launch_bounds__(256) void partition_kernel(
    const int* __restrict__ s0, const int* __restrict__ d0,
    const int* __restrict__ s1, const int* __restrict__ d1,
    const int* __restrict__ s2, const int* __restrict__ d2,
    int* __restrict__ gcursor, int* __restrict__ pairs,
    int NB, int NA, int E, int total) {
    __shared__ int hist[1024];
    __shared__ int gbase[1024];
    __shared__ int ssum[256];
    __shared__ int2 buf[TILE];   // {packed, bkt}
    int tid = threadIdx.x;
    for (int tile = blockIdx.x * TILE; tile < total; tile += gridDim.x * TILE) {
        for (int i = tid; i < 1024; i += 256) hist[i] = 0;
        __syncthreads();
        int cnt = min(TILE, total - tile);
        int mybkt[32], mypk[32], myrank[32];
#pragma unroll
        for (int j = 0; j < 32; j++) {
            int idx = tile + j * 256 + tid;
            int g = -1, s = 0;
            if (idx < total) {
                if (idx < E) { s = s0[idx]; g = d0[idx]; }
                else if (idx < 2 * E) { s = s1[idx - E]; g = NB + d1[idx - E]; }
                else { s = s2[idx - 2 * E]; g = NB + NA + d2[idx - 2 * E]; }
            }
            if (g >= 0) {
                mybkt[j] = g >> BSHIFT;
                mypk[j] = ((g & ((1 << BSHIFT) - 1)) << 17) | s;
                myrank[j] = atomicAdd(&hist[mybkt[j]], 1);
            } else mybkt[j] = -1;
        }
        __syncthreads();
        int l[4]; int base4 = tid * 4; int ts = 0;
#pragma unroll
        for (int j = 0; j < 4; j++) { l[j] = hist[base4 + j]; ts += l[j]; }
        ssum[tid] = ts; __syncthreads();
        for (int off = 1; off < 256; off <<= 1) {
            int t = (tid >= off) ? ssum[tid - off] : 0; __syncthreads();
            ssum[tid] += t; __syncthreads();
        }
        int exc = tid ? ssum[tid - 1] : 0;
#pragma unroll
        for (int j = 0; j < 4; j++) {
            hist[base4 + j] = exc;
            if (l[j]) gbase[base4 + j] = atomicAdd(&gcursor[base4 + j], l[j]);
            exc += l[j];
        }
        __syncthreads();
#pragma unroll
        for (int j = 0; j < 32; j++) {
            if (mybkt[j] >= 0)
                buf[hist[mybkt[j]] + myrank[j]] = make_int2(mypk[j], mybkt[j]);
        }
        __syncthreads();
        for (int i = tid; i < cnt; i += 256) {
            int2 p = buf[i];
            pairs[gbase[p.y] + (i - hist[p.y])] = p.x;
        }
        __syncthreads();
    }
}

// bucket b: order pairs into colidx segments; emit per-row [off_s, off_e).
__global__ __launch_bounds__(256) void bucket_fill(const int* __restrict__ pairs,
                                                   const int* __restrict__ gcursor,
                                                   int* __restrict__ off_s,
                                                   int* __restrict__ off_e,
                                                   int* __restrict__ colidx, int M) {
    int b = blockIdx.x;
    int gb = b << BSHIFT;
    __shared__ int cnt[512], cur[512], ssum[256];
    int tid = threadIdx.x;
    int p0 = b * CAP, p1 = gcursor[b];
    for (int i = tid; i < 512; i += 256) cnt[i] = 0;
    __syncthreads();
    for (int e = p0 + tid; e < p1; e += 256)
        atomicAdd(&cnt[(unsigned)pairs[e] >> 17], 1);
    __syncthreads();
    int l0 = cnt[tid * 2], l1 = cnt[tid * 2 + 1];
    ssum[tid] = l0 + l1; __syncthreads();
    for (int o = 1; o < 256; o <<= 1) {
        int t = (tid >= o) ? ssum[tid - o] : 0; __syncthreads();
        ssum[tid] += t; __syncthreads();
    }
    int exc = tid ? ssum[tid - 1] : 0;
    cur[tid * 2] = exc;
    cur[tid * 2 + 1] = exc + l0;
    int g0 = gb + tid * 2, g1 = g0 + 1;
    if (g0 < M) { off_s[g0] = p0 + exc;      off_e[g0] = p0 + exc + l0; }
    if (g1 < M) { off_s[g1] = p0 + exc + l0; off_e[g1] = p0 + exc + l0 + l1; }
    __syncthreads();
    for (int e = p0 + tid; e < p1; e += 256) {
        int p = pairs[e];
        int pos = atomicAdd(&cur[(unsigned)p >> 17], 1);
        colidx[p0 + pos] = p & 0x1FFFF;
    }
}

// ---------------- gather-mean: one row per 8-lane octet, dwordx4, 4-deep pipeline ----
// Each wave owns 8 consecutive dst rows (one per octet). A row is 64 bf16 =
// 128 B = 8 lanes x 16 B. Each lane accumulates its own 8 features in registers;
// no cross-lane reduction. Bound by random-row L2-miss BW (2-deep vs 4-deep = noise).
__device__ __forceinline__ void acc8(uint4 u, f32x4& a0, f32x4& a1) {
    a0[0] += uif(u.x << 16); a0[1] += uif(u.x & 0xFFFF0000u);
    a0[2] += uif(u.y << 16); a0[3] += uif(u.y & 0xFFFF0000u);
    a1[0] += uif(u.z << 16); a1[1] += uif(u.z & 0xFFFF0000u);
    a1[2] += uif(u.w << 16); a1[3] += uif(u.w & 0xFFFF0000u);
}

__global__ __launch_bounds__(256) void gather_all(const u16* __restrict__ plane,
                                                  const int* __restrict__ colidx,
                                                  const int* __restrict__ off_s,
                                                  const int* __restrict__ off_e,
                                                  u16* __restrict__ meanB,
                                                  u16* __restrict__ meanA1,
                                                  u16* __restrict__ meanA2,
                                                  int NB, int NA) {
    int wid = (blockIdx.x * 256 + threadIdx.x) >> 6;   // wave id
    int lane = threadIdx.x & 63;
    int oct = lane >> 3, fl = lane & 7;
    int M = NB + 2 * NA;
    int grow = wid * 8 + oct;
    if (grow >= M) return;

    const char* tab;
    u16* outp;
    int orow;
    if (grow < NB) { tab = (const char*)plane; outp = meanB; orow = grow; }
    else if (grow < NB + NA) { tab = (const char*)(plane + (size_t)NA * 64); outp = meanA1; orow = grow - NB; }
    else { tab = (const char*)plane; outp = meanA2; orow = grow - NB - NA; }

    int s0 = off_s[grow], s1 = off_e[grow];
    unsigned fo = (unsigned)(fl << 4);                 // byte offset within row
    f32x4 a0 = {0.f, 0.f, 0.f, 0.f}, a1 = {0.f, 0.f, 0.f, 0.f};

    int e = s0;
    if (e + 3 < s1) {
        int c0 = colidx[e], c1 = colidx[e + 1];
        int c2 = colidx[e + 2], c3 = colidx[e + 3];
        while (e + 7 < s1) {
            uint4 u0 = *(const uint4*)(tab + (((unsigned)c0 << 7) | fo));
            uint4 u1 = *(const uint4*)(tab + (((unsigned)c1 << 7) | fo));
            uint4 u2 = *(const uint4*)(tab + (((unsigned)c2 << 7) | fo));
            uint4 u3 = *(const uint4*)(tab + (((unsigned)c3 << 7) | fo));
            c0 = colidx[e + 4]; c1 = colidx[e + 5];    // prefetch next quad
            c2 = colidx[e + 6]; c3 = colidx[e + 7];
            acc8(u0, a0, a1); acc8(u1, a0, a1);
            acc8(u2, a0, a1); acc8(u3, a0, a1);
            e += 4;
        }
        {   // drain the pipelined quad
            uint4 u0 = *(const uint4*)(tab + (((unsigned)c0 << 7) | fo));
            uint4 u1 = *(const uint4*)(tab + (((unsigned)c1 << 7) | fo));
            uint4 u2 = *(const uint4*)(tab + (((unsigned)c2 << 7) | fo));
            uint4 u3 = *(const uint4*)(tab + (((unsigned)c3 << 7) | fo));
            acc8(u0, a0, a1); acc8(u1, a0, a1);
            acc8(u2, a0, a1); acc8(u3, a0, a1);
            e += 4;
        }
    }
    for (; e < s1; ++e) {                              // up to 3 leftovers
        int c = colidx[e];
        uint4 u = *(const uint4*)(tab + (((unsigned)c << 7) | fo));
        acc8(u, a0, a1);
    }

    float inv = 1.0f / fmaxf((float)(s1 - s0), 1.0f);
    u16 o[8];
#pragma unroll
    for (int i = 0; i < 4; i++) o[i] = (u16)f2bs(a0[i] * inv);
#pragma unroll
    for (int i = 0; i < 4; i++) o[4 + i] = (u16)f2bs(a1[i] * inv);
    *(uint4*)(outp + (size_t)orow * 64 + fl * 8) = *(uint4*)o;
}

// ---------------- fused linear body (bf16 in, MFMA, bf16 or f32 out) ----------------
// A[m=lane&15][k=(lane>>4)*8+j], B[k][n=lane&15] (pre-transposed),
// C/D row=(lane>>4)*4+reg, col=lane&15.
template <int NM, int RELU, int OUTF32>
__device__ __forceinline__ void lin_body(
    const u16* __restrict__ m0, const u16* __restrict__ m1,
    const u16* __restrict__ x,
    const u16* __restrict__ Wm0t, const u16* __restrict__ Wm1t,
    const u16* __restrict__ Wxt,
    const float* __restrict__ bias0, const float* __restrict__ bias1,
    void* __restrict__ outv, int nrows, int blk) {
    const int lane = threadIdx.x & 63;
    const int wave = threadIdx.x >> 6;
    const int row0 = blk * 64 + wave * 16;
    if (row0 >= nrows) return;
    const int r = lane & 15;
    const int q = lane >> 4;

    short8 wm0f[2][4], wm1f[2][4], wxf[2][4];
#pragma unroll
    for (int ks = 0; ks < 2; ks++) {
#pragma unroll
        for (int t = 0; t < 4; t++) {
            size_t widx = (size_t)(t * 16 + r) * 64 + ks * 32 + q * 8;
            if (NM >= 1) wm0f[ks][t] = *(const short8*)(Wm0t + widx);
            if (NM >= 2) wm1f[ks][t] = *(const short8*)(Wm1t + widx);
            wxf[ks][t] = *(const short8*)(Wxt + widx);
        }
    }

    f32x4 acc[4];
#pragma unroll
    for (int t = 0; t < 4; t++) {
        float bv = bias0[t * 16 + r];
        if (bias1) bv += bias1[t * 16 + r];
        acc[t][0] = bv; acc[t][1] = bv; acc[t][2] = bv; acc[t][3] = bv;
    }

    const int arow = row0 + r;
    const bool avalid = arow < nrows;
    short8 zf;
#pragma unroll
    for (int j = 0; j < 8; j++) zf[j] = 0;

    if (NM >= 1) {
#pragma unroll
        for (int ks = 0; ks < 2; ks++) {
            short8 af = avalid ? *(const short8*)(m0 + (size_t)arow * 64 + ks * 32 + q * 8) : zf;
#pragma unroll
            for (int t = 0; t < 4; t++)
                acc[t] = __builtin_amdgcn_mfma_f32_16x16x32_bf16(af, wm0f[ks][t], acc[t], 0, 0, 0);
        }
    }
    if (NM >= 2) {
#pragma unroll
        for (int ks = 0; ks < 2; ks++) {
            short8 af = avalid ? *(const short8*)(m1 + (size_t)arow * 64 + ks * 32 + q * 8) : zf;
#pragma unroll
            for (int t = 0; t < 4; t++)
                acc[t] = __builtin_amdgcn_mfma_f32_16x16x32_bf16(af, wm1f[ks][t], acc[t], 0, 0, 0);
        }
    }
#pragma unroll
    for (int ks = 0; ks < 2; ks++) {
        short8 xf = avalid ? *(const short8*)(x + (size_t)arow * 64 + ks * 32 + q * 8) : zf;
#pragma unroll
        for (int t = 0; t < 4; t++)
            acc[t] = __builtin_amdgcn_mfma_f32_16x16x32_bf16(xf, wxf[ks][t], acc[t], 0, 0, 0);
    }

#pragma unroll
    for (int t = 0; t < 4; t++) {
#pragma unroll
        for (int rr = 0; rr < 4; rr++) {
            int row = row0 + q * 4 + rr;
            if (row < nrows) {
                float v = acc[t][rr];
                if (RELU) v = fmaxf(v, 0.0f);
                if (OUTF32) ((float*)outv)[(size_t)row * 64 + t * 16 + r] = v;
                else ((u16*)outv)[(size_t)row * 64 + t * 16 + r] = (u16)f2bs(v);
            }
        }
    }
}

// one layer: B-phase blocks [0,blocksB), A-phase blocks [blocksB, ...)
__global__ __launch_bounds__(256) void layer_kernel(
    const u16* __restrict__ plane_in, u16* __restrict__ plane_out,
    const u16* __restrict__ meanB, const u16* __restrict__ meanA1,
    const u16* __restrict__ meanA2, const u16* __restrict__ wh,
    const float* __restrict__ bvec, int l, int NA, int NB, int blocksB) {
    if ((int)blockIdx.x < blocksB) {
        // new_B = mean(A->B)@Wn[l,0] + x_B@Wr[l,0] + b[l,0]
        lin_body<1, 0, 0>(meanB, nullptr, plane_in + (size_t)NA * 64,
                          wh + (size_t)(l * 3 + 0) * 4096, nullptr,
                          wh + (size_t)(6 + l) * 4096,
                          bvec + (size_t)(l * 3 + 0) * 64, nullptr,
                          plane_out + (size_t)NA * 64, NB, blockIdx.x);
    } else {
        // new_A = mean(B->A)@Wn[l,1] + mean(A->A)@Wn[l,2] + x_A@(Wr[l,1]+Wr[l,2]) + b[l,1]+b[l,2]
        lin_body<2, 0, 0>(meanA1, meanA2, plane_in,
                          wh + (size_t)(l * 3 + 1) * 4096, wh + (size_t)(l * 3 + 2) * 4096,
                          wh + (size_t)(8 + l) * 4096,
                          bvec + (size_t)(l * 3 + 1) * 64, bvec + (size_t)(l * 3 + 2) * 64,
                          plane_out, NA, blockIdx.x - blocksB);
    }
}

// head over NA+NB contiguous rows
__global__ __launch_bounds__(256) void head_kernel(
    const u16* __restrict__ plane_in, const u16* __restrict__ wh,
    const float* __restrict__ b_out, float* __restrict__ out, int nrows) {
    lin_body<0, 1, 1>(nullptr, nullptr, plane_in,
                      nullptr, nullptr, wh + (size_t)10 * 4096,
                      b_out, nullptr, out, nrows, blockIdx.x);
}

// ---------------- launch ----------------
extern "C" void kernel_launch(void* const* d_in, const int* in_sizes, int n_in,
                              void* d_out, int out_size, void* d_ws, size_t ws_size,
                              hipStream_t stream) {
    const float* xA_in = (const float*)d_in[0];
    const float* xB_in = (const float*)d_in[1];
    const float* Wn = (const float*)d_in[2];
    const float* Wr = (const float*)d_in[3];
    const float* b = (const float*)d_in[4];
    const float* W_out = (const float*)d_in[5];
    const float* b_out = (const float*)d_in[6];
    const int* src0 = (const int*)d_in[7];
    const int* dst0 = (const int*)d_in[8];
    const int* src1 = (const int*)d_in[9];
    const int* dst1 = (const int*)d_in[10];
    const int* src2 = (const int*)d_in[11];
    const int* dst2 = (const int*)d_in[12];

    const int NA = in_sizes[0] / 64;
    const int NB = in_sizes[1] / 64;
    const int E = in_sizes[7];
    const int M = NB + NA + NA;
    const int total = 3 * E;
    const int K = (M + (1 << BSHIFT) - 1) >> BSHIFT;   // 586 for 300k dst rows

    // ---- workspace ----
    const size_t PL = (size_t)(NA + NB) * 64;
    u16* plane[2];
    plane[0] = (u16*)d_ws;
    plane[1] = plane[0] + PL;
    u16* wh     = plane[1] + PL;                 // 11*4096
    u16* meanB  = wh + 11 * 4096;
    u16* meanA1 = meanB + (size_t)NB * 64;
    u16* meanA2 = meanA1 + (size_t)NA * 64;
    int* gcursor= (int*)(meanA2 + (size_t)NA * 64); // K (alloc 1024)
    int* off_s  = gcursor + 1024;                // M
    int* off_e  = off_s + M;                     // M
    int* colidx = off_e + M;                     // K*CAP (bucket-padded)
    int* pairs  = (int*)meanB;                   // K*CAP, aliases means (dead until gathers)

    // ---- prep (convert + weights) ----
    int bA = (NA * 16 + 255) / 256, bB = (NB * 16 + 255) / 256;
    prep_convert<<<bA + bB + 11, 256, 0, stream>>>(
        xA_in, xB_in, Wn, Wr, W_out, plane[0], wh, NA, NB);

    // ---- CSR build: fixed-capacity buckets, no counting pass ----
    init_cursor<<<(K + 255) / 256, 256, 0, stream>>>(gcursor, K);
    int ntiles = (total + TILE - 1) / TILE;
    partition_kernel<<<ntiles, 256, 0, stream>>>(src0, dst0, src1, dst1, src2, dst2,
                                                 gcursor, pairs, NB, NA, E, total);
    bucket_fill<<<K, 256, 0, stream>>>(pairs, gcursor, off_s, off_e, colidx, M);

    // ---- layers: separate high-occupancy gather + MFMA layer ----
    const int blocksB = (NB + 63) / 64;
    const int blocksA = (NA + 63) / 64;
    int p = 0;
    for (int l = 0; l < 2; l++) {
        gather_all<<<(M + 31) / 32, 256, 0, stream>>>(plane[p], colidx, off_s, off_e,
                                                      meanB, meanA1, meanA2, NB, NA);
        layer_kernel<<<blocksB + blocksA, 256, 0, stream>>>(
            plane[p], plane[1 - p], meanB, meanA1, meanA2, wh, b, l, NA, NB, blocksB);
        p = 1 - p;
    }

    // ---- head ----
    head_kernel<<<(NA + NB + 63) / 64, 256, 0, stream>>>(
        plane[p], wh, b_out, (float*)d_out, NA + NB);
}

// Round 7
// 427.210 us; speedup vs baseline: 6.7637x; 1.0306x over previous
//
#include <hip/hip_runtime.h>
#include <hip/hip_bf16.h>

typedef __bf16 bf16_t;
typedef unsigned short u16;
typedef short short8 __attribute__((ext_vector_type(8)));
typedef float f32x4 __attribute__((ext_vector_type(4)));

#define BSHIFT 9            // 512 dst-rows per bucket
#define CAP 8192            // fixed slots per bucket (expected 6144 +- 78; 26 sigma)
#define TILE 4096           // edges per partition tile (no LDS staging -> small tiles ok)

__device__ inline short f2bs(float v) {
    bf16_t h = (bf16_t)v;
    return __builtin_bit_cast(short, h);
}
__device__ inline float uif(unsigned u) { return __builtin_bit_cast(float, u); }

// ---------------- prep: f32->bf16 plane convert + weight transpose ----------------
// wh mats (transposed [n*64+k]): 0..5 Wn[l*3+e]; 6,7 WrB[l]=Wr[l,0];
// 8,9 WrA[l]=Wr[l,1]+Wr[l,2] (f32 pre-sum); 10 W_out.
__global__ __launch_bounds__(256) void prep_convert(
    const float* __restrict__ xA, const float* __restrict__ xB,
    const float* __restrict__ Wn, const float* __restrict__ Wr,
    const float* __restrict__ Wout,
    u16* __restrict__ plane0, u16* __restrict__ wh, int NA, int NB) {
    int nA4 = NA * 16, nB4 = NB * 16;
    int bA = (nA4 + 255) / 256, bB = (nB4 + 255) / 256;
    int bi = blockIdx.x;
    int tid = threadIdx.x;
    if (bi < bA + bB) {
        const float* in = (bi < bA) ? xA : xB;
        u16* out = (bi < bA) ? plane0 : plane0 + (size_t)NA * 64;
        int i = (bi < bA ? bi : bi - bA) * 256 + tid;
        int n4 = (bi < bA) ? nA4 : nB4;
        if (i >= n4) return;
        float4 v = ((const float4*)in)[i];
        u16 o[4];
        o[0] = (u16)f2bs(v.x); o[1] = (u16)f2bs(v.y);
        o[2] = (u16)f2bs(v.z); o[3] = (u16)f2bs(v.w);
        *(uint2*)(out + (size_t)i * 4) = *(uint2*)o;
        return;
    }
    int mat = bi - bA - bB;      // 0..10
    u16* dstp = wh + (size_t)mat * 4096;
    for (int i = tid; i < 4096; i += 256) {
        int k = i >> 6, n = i & 63;
        float v;
        if (mat < 6) v = Wn[(size_t)mat * 4096 + i];
        else if (mat < 8) v = Wr[(size_t)((mat - 6) * 3 + 0) * 4096 + i];
        else if (mat < 10) v = Wr[(size_t)((mat - 8) * 3 + 1) * 4096 + i]
                             + Wr[(size_t)((mat - 8) * 3 + 2) * 4096 + i];
        else v = Wout[i];
        dstp[n * 64 + k] = (u16)f2bs(v);
    }
}

__global__ __launch_bounds__(256) void init_cursor(int* __restrict__ gcursor, int K) {
    int i = blockIdx.x * 256 + threadIdx.x;
    if (i < K) gcursor[i] = i * CAP;
}

// pairs entry: packed = ((g & 511) << 17) | src   (src < 2^17, bucket = g >> 9)
// bucket b's region is [b*CAP, b*CAP + cnt_b) -- fixed capacity, no pre-count needed.
// Scan-free, staging-free: per tile, rank via LDS hist atomic; reserve per-bucket
// global range; write each element directly. A bucket's per-tile range is owned by
// ONE block, so scattered 4B writes coalesce in that block's L2 (no cross-XCD
// line ping-pong -- unlike the round-2 global-cursor scatter).
__global__ __launch_bounds__(256) void partition_kernel(
    const int* __restrict__ s0, const int* __restrict__ d0,
    const int* __restrict__ s1, const int* __restrict__ d1,
    const int* __restrict__ s2, const int* __restrict__ d2,
    int* __restrict__ gcursor, int* __restrict__ pairs,
    int NB, int NA, int E, int total) {
    __shared__ int hist[1024];
    __shared__ int gbase[1024];
    int tid = threadIdx.x;
    for (int tile = blockIdx.x * TILE; tile < total; tile += gridDim.x * TILE) {
        for (int i = tid; i < 1024; i += 256) hist[i] = 0;
        __syncthreads();
        int mybkt[16], mypk[16], myrank[16];
#pragma unroll
        for (int j = 0; j < 16; j++) {
            int idx = tile + j * 256 + tid;
            int g = -1, s = 0;
            if (idx < total) {
                if (idx < E) { s = s0[idx]; g = d0[idx]; }
                else if (idx < 2 * E) { s = s1[idx - E]; g = NB + d1[idx - E]; }
                else { s = s2[idx - 2 * E]; g = NB + NA + d2[idx - 2 * E]; }
            }
            if (g >= 0) {
                mybkt[j] = g >> BSHIFT;
                mypk[j] = ((g & ((1 << BSHIFT) - 1)) << 17) | s;
                myrank[j] = atomicAdd(&hist[mybkt[j]], 1);
            } else mybkt[j] = -1;
        }
        __syncthreads();
        for (int bq = tid; bq < 1024; bq += 256) {
            int c = hist[bq];
            if (c) gbase[bq] = atomicAdd(&gcursor[bq], c);
        }
        __syncthreads();
#pragma unroll
        for (int j = 0; j < 16; j++) {
            if (mybkt[j] >= 0)
                pairs[gbase[mybkt[j]] + myrank[j]] = mypk[j];
        }
        __syncthreads();   // hist/gbase stable before next iteration's zeroing
    }
}

// bucket b: order pairs into colidx segments; emit per-row [off_s, off_e).
// 512 threads = one row per thread; wave-shuffle scan (3 barriers, no ladder).
__global__ __launch_bounds__(512) void bucket_fill(const int* __restrict__ pairs,
                                                   const int* __restrict__ gcursor,
                                                   int* __restrict__ off_s,
                                                   int* __restrict__ off_e,
                                                   int* __restrict__ colidx, int M) {
    int b = blockIdx.x;
    int gb = b << BSHIFT;
    __shared__ int cnt[512], cur[512], wsum[8];
    int tid = threadIdx.x;
    int lane = tid & 63, w = tid >> 6;
    int p0 = b * CAP, p1 = gcursor[b];
    cnt[tid] = 0;
    __syncthreads();
    for (int e = p0 + tid; e < p1; e += 512)
        atomicAdd(&cnt[(unsigned)pairs[e] >> 17], 1);
    __syncthreads();
    int v = cnt[tid];
    int x = v;
#pragma unroll
    for (int off = 1; off < 64; off <<= 1) {
        int n = __shfl_up(x, off);
        if (lane >= off) x += n;
    }
    if (lane == 63) wsum[w] = x;
    __syncthreads();
    if (tid == 0) {
        int s = 0;
#pragma unroll
        for (int i = 0; i < 8; i++) { int t = wsum[i]; wsum[i] = s; s += t; }
    }
    __syncthreads();
    int excl = x - v + wsum[w];          // exclusive prefix of cnt over 512 rows
    cur[tid] = excl;
    int g = gb + tid;
    if (g < M) { off_s[g] = p0 + excl; off_e[g] = p0 + excl + v; }
    __syncthreads();
    for (int e = p0 + tid; e < p1; e += 512) {
        int p = pairs[e];
        int pos = atomicAdd(&cur[(unsigned)p >> 17], 1);
        colidx[p0 + pos] = p & 0x1FFFF;
    }
}

// ---------------- gather-mean: one row per 8-lane octet, dwordx4, 4-deep pipeline ----
// Each wave owns 8 consecutive dst rows (one per octet). A row is 64 bf16 =
// 128 B = 8 lanes x 16 B. Each lane accumulates its own 8 features in registers;
// no cross-lane reduction. Bound by random-row L2-miss BW (2-deep vs 4-deep = noise).
__device__ __forceinline__ void acc8(uint4 u, f32x4& a0, f32x4& a1) {
    a0[0] += uif(u.x << 16); a0[1] += uif(u.x & 0xFFFF0000u);
    a0[2] += uif(u.y << 16); a0[3] += uif(u.y & 0xFFFF0000u);
    a1[0] += uif(u.z << 16); a1[1] += uif(u.z & 0xFFFF0000u);
    a1[2] += uif(u.w << 16); a1[3] += uif(u.w & 0xFFFF0000u);
}

__global__ __launch_bounds__(256) void gather_all(const u16* __restrict__ plane,
                                                  const int* __restrict__ colidx,
                                                  const int* __restrict__ off_s,
                                                  const int* __restrict__ off_e,
                                                  u16* __restrict__ meanB,
                                                  u16* __restrict__ meanA1,
                                                  u16* __restrict__ meanA2,
                                                  int NB, int NA) {
    int wid = (blockIdx.x * 256 + threadIdx.x) >> 6;   // wave id
    int lane = threadIdx.x & 63;
    int oct = lane >> 3, fl = lane & 7;
    int M = NB + 2 * NA;
    int grow = wid * 8 + oct;
    if (grow >= M) return;

    const char* tab;
    u16* outp;
    int orow;
    if (grow < NB) { tab = (const char*)plane; outp = meanB; orow = grow; }
    else if (grow < NB + NA) { tab = (const char*)(plane + (size_t)NA * 64); outp = meanA1; orow = grow - NB; }
    else { tab = (const char*)plane; outp = meanA2; orow = grow - NB - NA; }

    int s0 = off_s[grow], s1 = off_e[grow];
    unsigned fo = (unsigned)(fl << 4);                 // byte offset within row
    f32x4 a0 = {0.f, 0.f, 0.f, 0.f}, a1 = {0.f, 0.f, 0.f, 0.f};

    int e = s0;
    if (e + 3 < s1) {
        int c0 = colidx[e], c1 = colidx[e + 1];
        int c2 = colidx[e + 2], c3 = colidx[e + 3];
        while (e + 7 < s1) {
            uint4 u0 = *(const uint4*)(tab + (((unsigned)c0 << 7) | fo));
            uint4 u1 = *(const uint4*)(tab + (((unsigned)c1 << 7) | fo));
            uint4 u2 = *(const uint4*)(tab + (((unsigned)c2 << 7) | fo));
            uint4 u3 = *(const uint4*)(tab + (((unsigned)c3 << 7) | fo));
            c0 = colidx[e + 4]; c1 = colidx[e + 5];    // prefetch next quad
            c2 = colidx[e + 6]; c3 = colidx[e + 7];
            acc8(u0, a0, a1); acc8(u1, a0, a1);
            acc8(u2, a0, a1); acc8(u3, a0, a1);
            e += 4;
        }
        {   // drain the pipelined quad
            uint4 u0 = *(const uint4*)(tab + (((unsigned)c0 << 7) | fo));
            uint4 u1 = *(const uint4*)(tab + (((unsigned)c1 << 7) | fo));
            uint4 u2 = *(const uint4*)(tab + (((unsigned)c2 << 7) | fo));
            uint4 u3 = *(const uint4*)(tab + (((unsigned)c3 << 7) | fo));
            acc8(u0, a0, a1); acc8(u1, a0, a1);
            acc8(u2, a0, a1); acc8(u3, a0, a1);
            e += 4;
        }
    }
    for (; e < s1; ++e) {                              // up to 3 leftovers
        int c = colidx[e];
        uint4 u = *(const uint4*)(tab + (((unsigned)c << 7) | fo));
        acc8(u, a0, a1);
    }

    float inv = 1.0f / fmaxf((float)(s1 - s0), 1.0f);
    u16 o[8];
#pragma unroll
    for (int i = 0; i < 4; i++) o[i] = (u16)f2bs(a0[i] * inv);
#pragma unroll
    for (int i = 0; i < 4; i++) o[4 + i] = (u16)f2bs(a1[i] * inv);
    *(uint4*)(outp + (size_t)orow * 64 + fl * 8) = *(uint4*)o;
}

// ---------------- fused linear body (bf16 in, MFMA, bf16 or f32 out) ----------------
// A[m=lane&15][k=(lane>>4)*8+j], B[k][n=lane&15] (pre-transposed),
// C/D row=(lane>>4)*4+reg, col=lane&15.
template <int NM, int RELU, int OUTF32>
__device__ __forceinline__ void lin_body(
    const u16* __restrict__ m0, const u16* __restrict__ m1,
    const u16* __restrict__ x,
    const u16* __restrict__ Wm0t, const u16* __restrict__ Wm1t,
    const u16* __restrict__ Wxt,
    const float* __restrict__ bias0, const float* __restrict__ bias1,
    void* __restrict__ outv, int nrows, int blk) {
    const int lane = threadIdx.x & 63;
    const int wave = threadIdx.x >> 6;
    const int row0 = blk * 64 + wave * 16;
    if (row0 >= nrows) return;
    const int r = lane & 15;
    const int q = lane >> 4;

    short8 wm0f[2][4], wm1f[2][4], wxf[2][4];
#pragma unroll
    for (int ks = 0; ks < 2; ks++) {
#pragma unroll
        for (int t = 0; t < 4; t++) {
            size_t widx = (size_t)(t * 16 + r) * 64 + ks * 32 + q * 8;
            if (NM >= 1) wm0f[ks][t] = *(const short8*)(Wm0t + widx);
            if (NM >= 2) wm1f[ks][t] = *(const short8*)(Wm1t + widx);
            wxf[ks][t] = *(const short8*)(Wxt + widx);
        }
    }

    f32x4 acc[4];
#pragma unroll
    for (int t = 0; t < 4; t++) {
        float bv = bias0[t * 16 + r];
        if (bias1) bv += bias1[t * 16 + r];
        acc[t][0] = bv; acc[t][1] = bv; acc[t][2] = bv; acc[t][3] = bv;
    }

    const int arow = row0 + r;
    const bool avalid = arow < nrows;
    short8 zf;
#pragma unroll
    for (int j = 0; j < 8; j++) zf[j] = 0;

    if (NM >= 1) {
#pragma unroll
        for (int ks = 0; ks < 2; ks++) {
            short8 af = avalid ? *(const short8*)(m0 + (size_t)arow * 64 + ks * 32 + q * 8) : zf;
#pragma unroll
            for (int t = 0; t < 4; t++)
                acc[t] = __builtin_amdgcn_mfma_f32_16x16x32_bf16(af, wm0f[ks][t], acc[t], 0, 0, 0);
        }
    }
    if (NM >= 2) {
#pragma unroll
        for (int ks = 0; ks < 2; ks++) {
            short8 af = avalid ? *(const short8*)(m1 + (size_t)arow * 64 + ks * 32 + q * 8) : zf;
#pragma unroll
            for (int t = 0; t < 4; t++)
                acc[t] = __builtin_amdgcn_mfma_f32_16x16x32_bf16(af, wm1f[ks][t], acc[t], 0, 0, 0);
        }
    }
#pragma unroll
    for (int ks = 0; ks < 2; ks++) {
        short8 xf = avalid ? *(const short8*)(x + (size_t)arow * 64 + ks * 32 + q * 8) : zf;
#pragma unroll
        for (int t = 0; t < 4; t++)
            acc[t] = __builtin_amdgcn_mfma_f32_16x16x32_bf16(xf, wxf[ks][t], acc[t], 0, 0, 0);
    }

#pragma unroll
    for (int t = 0; t < 4; t++) {
#pragma unroll
        for (int rr = 0; rr < 4; rr++) {
            int row = row0 + q * 4 + rr;
            if (row < nrows) {
                float v = acc[t][rr];
                if (RELU) v = fmaxf(v, 0.0f);
                if (OUTF32) ((float*)outv)[(size_t)row * 64 + t * 16 + r] = v;
                else ((u16*)outv)[(size_t)row * 64 + t * 16 + r] = (u16)f2bs(v);
            }
        }
    }
}

// one layer: B-phase blocks [0,blocksB), A-phase blocks [blocksB, ...)
__global__ __launch_bounds__(256) void layer_kernel(
    const u16* __restrict__ plane_in, u16* __restrict__ plane_out,
    const u16* __restrict__ meanB, const u16* __restrict__ meanA1,
    const u16* __restrict__ meanA2, const u16* __restrict__ wh,
    const float* __restrict__ bvec, int l, int NA, int NB, int blocksB) {
    if ((int)blockIdx.x < blocksB) {
        // new_B = mean(A->B)@Wn[l,0] + x_B@Wr[l,0] + b[l,0]
        lin_body<1, 0, 0>(meanB, nullptr, plane_in + (size_t)NA * 64,
                          wh + (size_t)(l * 3 + 0) * 4096, nullptr,
                          wh + (size_t)(6 + l) * 4096,
                          bvec + (size_t)(l * 3 + 0) * 64, nullptr,
                          plane_out + (size_t)NA * 64, NB, blockIdx.x);
    } else {
        // new_A = mean(B->A)@Wn[l,1] + mean(A->A)@Wn[l,2] + x_A@(Wr[l,1]+Wr[l,2]) + b[l,1]+b[l,2]
        lin_body<2, 0, 0>(meanA1, meanA2, plane_in,
                          wh + (size_t)(l * 3 + 1) * 4096, wh + (size_t)(l * 3 + 2) * 4096,
                          wh + (size_t)(8 + l) * 4096,
                          bvec + (size_t)(l * 3 + 1) * 64, bvec + (size_t)(l * 3 + 2) * 64,
                          plane_out, NA, blockIdx.x - blocksB);
    }
}

// head over NA+NB contiguous rows
__global__ __launch_bounds__(256) void head_kernel(
    const u16* __restrict__ plane_in, const u16* __restrict__ wh,
    const float* __restrict__ b_out, float* __restrict__ out, int nrows) {
    lin_body<0, 1, 1>(nullptr, nullptr, plane_in,
                      nullptr, nullptr, wh + (size_t)10 * 4096,
                      b_out, nullptr, out, nrows, blockIdx.x);
}

// ---------------- launch ----------------
extern "C" void kernel_launch(void* const* d_in, const int* in_sizes, int n_in,
                              void* d_out, int out_size, void* d_ws, size_t ws_size,
                              hipStream_t stream) {
    const float* xA_in = (const float*)d_in[0];
    const float* xB_in = (const float*)d_in[1];
    const float* Wn = (const float*)d_in[2];
    const float* Wr = (const float*)d_in[3];
    const float* b = (const float*)d_in[4];
    const float* W_out = (const float*)d_in[5];
    const float* b_out = (const float*)d_in[6];
    const int* src0 = (const int*)d_in[7];
    const int* dst0 = (const int*)d_in[8];
    const int* src1 = (const int*)d_in[9];
    const int* dst1 = (const int*)d_in[10];
    const int* src2 = (const int*)d_in[11];
    const int* dst2 = (const int*)d_in[12];

    const int NA = in_sizes[0] / 64;
    const int NB = in_sizes[1] / 64;
    const int E = in_sizes[7];
    const int M = NB + NA + NA;
    const int total = 3 * E;
    const int K = (M + (1 << BSHIFT) - 1) >> BSHIFT;   // 586 for 300k dst rows

    // ---- workspace ----
    const size_t PL = (size_t)(NA + NB) * 64;
    u16* plane[2];
    plane[0] = (u16*)d_ws;
    plane[1] = plane[0] + PL;
    u16* wh     = plane[1] + PL;                 // 11*4096
    u16* meanB  = wh + 11 * 4096;
    u16* meanA1 = meanB + (size_t)NB * 64;
    u16* meanA2 = meanA1 + (size_t)NA * 64;
    int* gcursor= (int*)(meanA2 + (size_t)NA * 64); // K (alloc 1024)
    int* off_s  = gcursor + 1024;                // M
    int* off_e  = off_s + M;                     // M
    int* colidx = off_e + M;                     // K*CAP (bucket-padded)
    int* pairs  = (int*)meanB;                   // K*CAP, aliases means (dead until gathers)

    // ---- prep (convert + weights) ----
    int bA = (NA * 16 + 255) / 256, bB = (NB * 16 + 255) / 256;
    prep_convert<<<bA + bB + 11, 256, 0, stream>>>(
        xA_in, xB_in, Wn, Wr, W_out, plane[0], wh, NA, NB);

    // ---- CSR build: fixed-capacity buckets, scan-free partition ----
    init_cursor<<<(K + 255) / 256, 256, 0, stream>>>(gcursor, K);
    int ntiles = (total + TILE - 1) / TILE;
    partition_kernel<<<ntiles, 256, 0, stream>>>(src0, dst0, src1, dst1, src2, dst2,
                                                 gcursor, pairs, NB, NA, E, total);
    bucket_fill<<<K, 512, 0, stream>>>(pairs, gcursor, off_s, off_e, colidx, M);

    // ---- layers: separate high-occupancy gather + MFMA layer ----
    const int blocksB = (NB + 63) / 64;
    const int blocksA = (NA + 63) / 64;
    int p = 0;
    for (int l = 0; l < 2; l++) {
        gather_all<<<(M + 31) / 32, 256, 0, stream>>>(plane[p], colidx, off_s, off_e,
                                                      meanB, meanA1, meanA2, NB, NA);
        layer_kernel<<<blocksB + blocksA, 256, 0, stream>>>(
            plane[p], plane[1 - p], meanB, meanA1, meanA2, wh, b, l, NA, NB, blocksB);
        p = 1 - p;
    }

    // ---- head ----
    head_kernel<<<(NA + NB + 63) / 64, 256, 0, stream>>>(
        plane[p], wh, b_out, (float*)d_out, NA + NB);
}

// Round 8
// 414.441 us; speedup vs baseline: 6.9720x; 1.0308x over previous
//
#include <hip/hip_runtime.h>
#include <hip/hip_bf16.h>

typedef __bf16 bf16_t;
typedef unsigned short u16;
typedef short short8 __attribute__((ext_vector_type(8)));
typedef float f32x4 __attribute__((ext_vector_type(4)));

#define BSHIFT 9            // 512 dst-rows per bucket
#define CAP 8192            // fixed slots per bucket (expected 6144 +- 78; 26 sigma)
#define TILE 16384          // edges per partition tile (1024 thr x 16)

__device__ inline short f2bs(float v) {
    bf16_t h = (bf16_t)v;
    return __builtin_bit_cast(short, h);
}
__device__ inline float uif(unsigned u) { return __builtin_bit_cast(float, u); }

// ---------------- prep: plane convert + weight transpose + cursor init ----------------
// wh mats (transposed [n*64+k]): 0..5 Wn[l*3+e]; 6,7 WrB[l]=Wr[l,0];
// 8,9 WrA[l]=Wr[l,1]+Wr[l,2] (f32 pre-sum); 10 W_out.
__global__ __launch_bounds__(256) void prep_convert(
    const float* __restrict__ xA, const float* __restrict__ xB,
    const float* __restrict__ Wn, const float* __restrict__ Wr,
    const float* __restrict__ Wout,
    u16* __restrict__ plane0, u16* __restrict__ wh,
    int* __restrict__ gcursor, int NA, int NB, int K) {
    int nA4 = NA * 16, nB4 = NB * 16;
    int bA = (nA4 + 255) / 256, bB = (nB4 + 255) / 256;
    int bi = blockIdx.x;
    int tid = threadIdx.x;
    if (bi < bA + bB) {
        const float* in = (bi < bA) ? xA : xB;
        u16* out = (bi < bA) ? plane0 : plane0 + (size_t)NA * 64;
        int i = (bi < bA ? bi : bi - bA) * 256 + tid;
        int n4 = (bi < bA) ? nA4 : nB4;
        if (i >= n4) return;
        float4 v = ((const float4*)in)[i];
        u16 o[4];
        o[0] = (u16)f2bs(v.x); o[1] = (u16)f2bs(v.y);
        o[2] = (u16)f2bs(v.z); o[3] = (u16)f2bs(v.w);
        *(uint2*)(out + (size_t)i * 4) = *(uint2*)o;
        return;
    }
    if (bi < bA + bB + 11) {
        int mat = bi - bA - bB;      // 0..10
        u16* dstp = wh + (size_t)mat * 4096;
        for (int i = tid; i < 4096; i += 256) {
            int k = i >> 6, n = i & 63;
            float v;
            if (mat < 6) v = Wn[(size_t)mat * 4096 + i];
            else if (mat < 8) v = Wr[(size_t)((mat - 6) * 3 + 0) * 4096 + i];
            else if (mat < 10) v = Wr[(size_t)((mat - 8) * 3 + 1) * 4096 + i]
                                 + Wr[(size_t)((mat - 8) * 3 + 2) * 4096 + i];
            else v = Wout[i];
            dstp[n * 64 + k] = (u16)f2bs(v);
        }
        return;
    }
    // cursor init (last block)
    for (int i = tid; i < K; i += 256) gcursor[i] = i * CAP;
}

// pairs entry: packed = ((g & 511) << 17) | src   (src < 2^17, bucket = g >> 9)
// bucket b's region is [b*CAP, b*CAP + cnt_b). Scan-free: per tile, rank via LDS
// hist atomic; reserve per-bucket global range; write directly. TILE=16384 so a
// bucket's per-tile run is ~28 edges (~112 B) -> line-inflation ~1.6x, and the
// run is owned by ONE block (no cross-XCD ping-pong).
__global__ __launch_bounds__(1024) void partition_kernel(
    const int* __restrict__ s0, const int* __restrict__ d0,
    const int* __restrict__ s1, const int* __restrict__ d1,
    const int* __restrict__ s2, const int* __restrict__ d2,
    int* __restrict__ gcursor, int* __restrict__ pairs,
    int NB, int NA, int E, int total) {
    __shared__ int hist[1024];
    __shared__ int gbase[1024];
    int tid = threadIdx.x;
    for (int tile = blockIdx.x * TILE; tile < total; tile += gridDim.x * TILE) {
        hist[tid] = 0;
        __syncthreads();
        int mybkt[16], mypk[16], myrank[16];
#pragma unroll
        for (int j = 0; j < 16; j++) {
            int idx = tile + j * 1024 + tid;
            int g = -1, s = 0;
            if (idx < total) {
                if (idx < E) { s = s0[idx]; g = d0[idx]; }
                else if (idx < 2 * E) { s = s1[idx - E]; g = NB + d1[idx - E]; }
                else { s = s2[idx - 2 * E]; g = NB + NA + d2[idx - 2 * E]; }
            }
            if (g >= 0) {
                mybkt[j] = g >> BSHIFT;
                mypk[j] = ((g & ((1 << BSHIFT) - 1)) << 17) | s;
                myrank[j] = atomicAdd(&hist[mybkt[j]], 1);
            } else mybkt[j] = -1;
        }
        __syncthreads();
        {
            int c = hist[tid];
            if (c) gbase[tid] = atomicAdd(&gcursor[tid], c);
        }
        __syncthreads();
#pragma unroll
        for (int j = 0; j < 16; j++) {
            if (mybkt[j] >= 0)
                pairs[gbase[mybkt[j]] + myrank[j]] = mypk[j];
        }
        __syncthreads();   // hist/gbase stable before next iteration's zeroing
    }
}

// bucket b: order pairs into colidx segments; emit per-row [off_s, off_e).
// 512 threads = one row per thread; wave-shuffle scan (3 barriers).
__global__ __launch_bounds__(512) void bucket_fill(const int* __restrict__ pairs,
                                                   const int* __restrict__ gcursor,
                                                   int* __restrict__ off_s,
                                                   int* __restrict__ off_e,
                                                   int* __restrict__ colidx, int M) {
    int b = blockIdx.x;
    int gb = b << BSHIFT;
    __shared__ int cnt[512], cur[512], wsum[8];
    int tid = threadIdx.x;
    int lane = tid & 63, w = tid >> 6;
    int p0 = b * CAP, p1 = gcursor[b];
    cnt[tid] = 0;
    __syncthreads();
    for (int e = p0 + tid; e < p1; e += 512)
        atomicAdd(&cnt[(unsigned)pairs[e] >> 17], 1);
    __syncthreads();
    int v = cnt[tid];
    int x = v;
#pragma unroll
    for (int off = 1; off < 64; off <<= 1) {
        int n = __shfl_up(x, off);
        if (lane >= off) x += n;
    }
    if (lane == 63) wsum[w] = x;
    __syncthreads();
    if (tid == 0) {
        int s = 0;
#pragma unroll
        for (int i = 0; i < 8; i++) { int t = wsum[i]; wsum[i] = s; s += t; }
    }
    __syncthreads();
    int excl = x - v + wsum[w];          // exclusive prefix of cnt over 512 rows
    cur[tid] = excl;
    int g = gb + tid;
    if (g < M) { off_s[g] = p0 + excl; off_e[g] = p0 + excl + v; }
    __syncthreads();
    for (int e = p0 + tid; e < p1; e += 512) {
        int p = pairs[e];
        int pos = atomicAdd(&cur[(unsigned)p >> 17], 1);
        colidx[p0 + pos] = p & 0x1FFFF;
    }
}

// ---------------- gather-mean: one row per 8-lane octet, dwordx4, 4-deep pipeline ----
// Bound by random-row L2-miss BW (59 us / 48% HBM, stable across rounds).
__device__ __forceinline__ void acc8(uint4 u, f32x4& a0, f32x4& a1) {
    a0[0] += uif(u.x << 16); a0[1] += uif(u.x & 0xFFFF0000u);
    a0[2] += uif(u.y << 16); a0[3] += uif(u.y & 0xFFFF0000u);
    a1[0] += uif(u.z << 16); a1[1] += uif(u.z & 0xFFFF0000u);
    a1[2] += uif(u.w << 16); a1[3] += uif(u.w & 0xFFFF0000u);
}

__global__ __launch_bounds__(256) void gather_all(const u16* __restrict__ plane,
                                                  const int* __restrict__ colidx,
                                                  const int* __restrict__ off_s,
                                                  const int* __restrict__ off_e,
                                                  u16* __restrict__ meanB,
                                                  u16* __restrict__ meanA1,
                                                  u16* __restrict__ meanA2,
                                                  int NB, int NA) {
    int wid = (blockIdx.x * 256 + threadIdx.x) >> 6;   // wave id
    int lane = threadIdx.x & 63;
    int oct = lane >> 3, fl = lane & 7;
    int M = NB + 2 * NA;
    int grow = wid * 8 + oct;
    if (grow >= M) return;

    const char* tab;
    u16* outp;
    int orow;
    if (grow < NB) { tab = (const char*)plane; outp = meanB; orow = grow; }
    else if (grow < NB + NA) { tab = (const char*)(plane + (size_t)NA * 64); outp = meanA1; orow = grow - NB; }
    else { tab = (const char*)plane; outp = meanA2; orow = grow - NB - NA; }

    int s0 = off_s[grow], s1 = off_e[grow];
    unsigned fo = (unsigned)(fl << 4);                 // byte offset within row
    f32x4 a0 = {0.f, 0.f, 0.f, 0.f}, a1 = {0.f, 0.f, 0.f, 0.f};

    int e = s0;
    if (e + 3 < s1) {
        int c0 = colidx[e], c1 = colidx[e + 1];
        int c2 = colidx[e + 2], c3 = colidx[e + 3];
        while (e + 7 < s1) {
            uint4 u0 = *(const uint4*)(tab + (((unsigned)c0 << 7) | fo));
            uint4 u1 = *(const uint4*)(tab + (((unsigned)c1 << 7) | fo));
            uint4 u2 = *(const uint4*)(tab + (((unsigned)c2 << 7) | fo));
            uint4 u3 = *(const uint4*)(tab + (((unsigned)c3 << 7) | fo));
            c0 = colidx[e + 4]; c1 = colidx[e + 5];    // prefetch next quad
            c2 = colidx[e + 6]; c3 = colidx[e + 7];
            acc8(u0, a0, a1); acc8(u1, a0, a1);
            acc8(u2, a0, a1); acc8(u3, a0, a1);
            e += 4;
        }
        {   // drain the pipelined quad
            uint4 u0 = *(const uint4*)(tab + (((unsigned)c0 << 7) | fo));
            uint4 u1 = *(const uint4*)(tab + (((unsigned)c1 << 7) | fo));
            uint4 u2 = *(const uint4*)(tab + (((unsigned)c2 << 7) | fo));
            uint4 u3 = *(const uint4*)(tab + (((unsigned)c3 << 7) | fo));
            acc8(u0, a0, a1); acc8(u1, a0, a1);
            acc8(u2, a0, a1); acc8(u3, a0, a1);
            e += 4;
        }
    }
    for (; e < s1; ++e) {                              // up to 3 leftovers
        int c = colidx[e];
        uint4 u = *(const uint4*)(tab + (((unsigned)c << 7) | fo));
        acc8(u, a0, a1);
    }

    float inv = 1.0f / fmaxf((float)(s1 - s0), 1.0f);
    u16 o[8];
#pragma unroll
    for (int i = 0; i < 4; i++) o[i] = (u16)f2bs(a0[i] * inv);
#pragma unroll
    for (int i = 0; i < 4; i++) o[4 + i] = (u16)f2bs(a1[i] * inv);
    *(uint4*)(outp + (size_t)orow * 64 + fl * 8) = *(uint4*)o;
}

// ---------------- linear bodies (bf16 in, MFMA) ----------------
// A[m=lane&15][k=(lane>>4)*8+j], B[k][n=lane&15] (pre-transposed),
// C/D row=(lane>>4)*4+reg, col=lane&15.

// layer-1 body: bf16 out to plane
template <int NM>
__device__ __forceinline__ void lin_body(
    const u16* __restrict__ m0, const u16* __restrict__ m1,
    const u16* __restrict__ x,
    const u16* __restrict__ Wm0t, const u16* __restrict__ Wm1t,
    const u16* __restrict__ Wxt,
    const float* __restrict__ bias0, const float* __restrict__ bias1,
    u16* __restrict__ outv, int nrows, int blk) {
    const int lane = threadIdx.x & 63;
    const int wave = threadIdx.x >> 6;
    const int row0 = blk * 64 + wave * 16;
    if (row0 >= nrows) return;
    const int r = lane & 15;
    const int q = lane >> 4;

    f32x4 acc[4];
#pragma unroll
    for (int t = 0; t < 4; t++) {
        float bv = bias0[t * 16 + r];
        if (NM >= 2) bv += bias1[t * 16 + r];
        acc[t][0] = bv; acc[t][1] = bv; acc[t][2] = bv; acc[t][3] = bv;
    }

    const int arow = row0 + r;
    const bool avalid = arow < nrows;
    short8 zf;
#pragma unroll
    for (int j = 0; j < 8; j++) zf[j] = 0;

#pragma unroll
    for (int ks = 0; ks < 2; ks++) {
        short8 af = avalid ? *(const short8*)(m0 + (size_t)arow * 64 + ks * 32 + q * 8) : zf;
        short8 xf = avalid ? *(const short8*)(x + (size_t)arow * 64 + ks * 32 + q * 8) : zf;
        short8 bf_;
        if (NM >= 2) bf_ = avalid ? *(const short8*)(m1 + (size_t)arow * 64 + ks * 32 + q * 8) : zf;
#pragma unroll
        for (int t = 0; t < 4; t++) {
            size_t widx = (size_t)(t * 16 + r) * 64 + ks * 32 + q * 8;
            acc[t] = __builtin_amdgcn_mfma_f32_16x16x32_bf16(af, *(const short8*)(Wm0t + widx), acc[t], 0, 0, 0);
            if (NM >= 2)
                acc[t] = __builtin_amdgcn_mfma_f32_16x16x32_bf16(bf_, *(const short8*)(Wm1t + widx), acc[t], 0, 0, 0);
            acc[t] = __builtin_amdgcn_mfma_f32_16x16x32_bf16(xf, *(const short8*)(Wxt + widx), acc[t], 0, 0, 0);
        }
    }

#pragma unroll
    for (int t = 0; t < 4; t++) {
#pragma unroll
        for (int rr = 0; rr < 4; rr++) {
            int row = row0 + q * 4 + rr;
            if (row < nrows)
                outv[(size_t)row * 64 + t * 16 + r] = (u16)f2bs(acc[t][rr]);
        }
    }
}

__global__ __launch_bounds__(256) void layer1_kernel(
    const u16* __restrict__ plane_in, u16* __restrict__ plane_out,
    const u16* __restrict__ meanB, const u16* __restrict__ meanA1,
    const u16* __restrict__ meanA2, const u16* __restrict__ wh,
    const float* __restrict__ bvec, int NA, int NB, int blocksB) {
    if ((int)blockIdx.x < blocksB) {
        lin_body<1>(meanB, nullptr, plane_in + (size_t)NA * 64,
                    wh + (size_t)0 * 4096, nullptr, wh + (size_t)6 * 4096,
                    bvec + (size_t)0 * 64, nullptr,
                    plane_out + (size_t)NA * 64, NB, blockIdx.x);
    } else {
        lin_body<2>(meanA1, meanA2, plane_in,
                    wh + (size_t)1 * 4096, wh + (size_t)2 * 4096, wh + (size_t)8 * 4096,
                    bvec + (size_t)1 * 64, bvec + (size_t)2 * 64,
                    plane_out, NA, blockIdx.x - blocksB);
    }
}

// layer-2 + head fused: compute y = conv2(...) in registers (bf16-rounded),
// LDS-transpose the 16x64 wave tile back to A-frag layout ([16][72] pad dodges
// the 128B-stride bank conflict), then out = relu(y @ W_out + b_out) in f32.
// No early return (barrier safety); guards on loads/stores instead.
template <int NM>
__device__ __forceinline__ void lin_body_head(
    const u16* __restrict__ m0, const u16* __restrict__ m1,
    const u16* __restrict__ x,
    const u16* __restrict__ Wm0t, const u16* __restrict__ Wm1t,
    const u16* __restrict__ Wxt,
    const float* __restrict__ bias0, const float* __restrict__ bias1,
    const u16* __restrict__ Woutt, const float* __restrict__ b_out,
    float* __restrict__ out, int nrows, int blk) {
    const int lane = threadIdx.x & 63;
    const int wave = threadIdx.x >> 6;
    const int row0 = blk * 64 + wave * 16;
    const int r = lane & 15;
    const int q = lane >> 4;
    const int arow = row0 + r;
    const bool avalid = (row0 < nrows) && (arow < nrows);

    __shared__ __align__(16) u16 xt[4][16][72];

    f32x4 acc[4];
#pragma unroll
    for (int t = 0; t < 4; t++) {
        float bv = bias0[t * 16 + r];
        if (NM >= 2) bv += bias1[t * 16 + r];
        acc[t][0] = bv; acc[t][1] = bv; acc[t][2] = bv; acc[t][3] = bv;
    }

    short8 zf;
#pragma unroll
    for (int j = 0; j < 8; j++) zf[j] = 0;

#pragma unroll
    for (int ks = 0; ks < 2; ks++) {
        short8 af = avalid ? *(const short8*)(m0 + (size_t)arow * 64 + ks * 32 + q * 8) : zf;
        short8 xf = avalid ? *(const short8*)(x + (size_t)arow * 64 + ks * 32 + q * 8) : zf;
        short8 bf_;
        if (NM >= 2) bf_ = avalid ? *(const short8*)(m1 + (size_t)arow * 64 + ks * 32 + q * 8) : zf;
#pragma unroll
        for (int t = 0; t < 4; t++) {
            size_t widx = (size_t)(t * 16 + r) * 64 + ks * 32 + q * 8;
            acc[t] = __builtin_amdgcn_mfma_f32_16x16x32_bf16(af, *(const short8*)(Wm0t + widx), acc[t], 0, 0, 0);
            if (NM >= 2)
                acc[t] = __builtin_amdgcn_mfma_f32_16x16x32_bf16(bf_, *(const short8*)(Wm1t + widx), acc[t], 0, 0, 0);
            acc[t] = __builtin_amdgcn_mfma_f32_16x16x32_bf16(xf, *(const short8*)(Wxt + widx), acc[t], 0, 0, 0);
        }
    }

    // stash y (bf16-rounded, same quantization as the unfused plane write)
#pragma unroll
    for (int t = 0; t < 4; t++)
#pragma unroll
        for (int rr = 0; rr < 4; rr++)
            xt[wave][q * 4 + rr][t * 16 + r] = (u16)f2bs(acc[t][rr]);
    __syncthreads();

    // head: A-frag from LDS, W_out pre-transposed
    f32x4 hacc[4];
#pragma unroll
    for (int t = 0; t < 4; t++) {
        float bv = b_out[t * 16 + r];
        hacc[t][0] = bv; hacc[t][1] = bv; hacc[t][2] = bv; hacc[t][3] = bv;
    }
#pragma unroll
    for (int ks = 0; ks < 2; ks++) {
        short8 yf = *(const short8*)&xt[wave][r][ks * 32 + q * 8];
#pragma unroll
        for (int t = 0; t < 4; t++) {
            size_t widx = (size_t)(t * 16 + r) * 64 + ks * 32 + q * 8;
            hacc[t] = __builtin_amdgcn_mfma_f32_16x16x32_bf16(yf, *(const short8*)(Woutt + widx), hacc[t], 0, 0, 0);
        }
    }
#pragma unroll
    for (int t = 0; t < 4; t++) {
#pragma unroll
        for (int rr = 0; rr < 4; rr++) {
            int row = row0 + q * 4 + rr;
            if (row < nrows)
                out[(size_t)row * 64 + t * 16 + r] = fmaxf(hacc[t][rr], 0.0f);
        }
    }
}

__global__ __launch_bounds__(256) void layer2_head_kernel(
    const u16* __restrict__ plane_in,
    const u16* __restrict__ meanB, const u16* __restrict__ meanA1,
    const u16* __restrict__ meanA2, const u16* __restrict__ wh,
    const float* __restrict__ bvec, const float* __restrict__ b_out,
    float* __restrict__ out, int NA, int NB, int blocksB) {
    const u16* Woutt = wh + (size_t)10 * 4096;
    if ((int)blockIdx.x < blocksB) {
        // new_B rows -> out rows [NA, NA+NB)
        lin_body_head<1>(meanB, nullptr, plane_in + (size_t)NA * 64,
                         wh + (size_t)3 * 4096, nullptr, wh + (size_t)7 * 4096,
                         bvec + (size_t)3 * 64, nullptr,
                         Woutt, b_out, out + (size_t)NA * 64, NB, blockIdx.x);
    } else {
        // new_A rows -> out rows [0, NA)
        lin_body_head<2>(meanA1, meanA2, plane_in,
                         wh + (size_t)4 * 4096, wh + (size_t)5 * 4096, wh + (size_t)9 * 4096,
                         bvec + (size_t)4 * 64, bvec + (size_t)5 * 64,
                         Woutt, b_out, out, NA, blockIdx.x - blocksB);
    }
}

// ---------------- launch ----------------
extern "C" void kernel_launch(void* const* d_in, const int* in_sizes, int n_in,
                              void* d_out, int out_size, void* d_ws, size_t ws_size,
                              hipStream_t stream) {
    const float* xA_in = (const float*)d_in[0];
    const float* xB_in = (const float*)d_in[1];
    const float* Wn = (const float*)d_in[2];
    const float* Wr = (const float*)d_in[3];
    const float* b = (const float*)d_in[4];
    const float* W_out = (const float*)d_in[5];
    const float* b_out = (const float*)d_in[6];
    const int* src0 = (const int*)d_in[7];
    const int* dst0 = (const int*)d_in[8];
    const int* src1 = (const int*)d_in[9];
    const int* dst1 = (const int*)d_in[10];
    const int* src2 = (const int*)d_in[11];
    const int* dst2 = (const int*)d_in[12];

    const int NA = in_sizes[0] / 64;
    const int NB = in_sizes[1] / 64;
    const int E = in_sizes[7];
    const int M = NB + NA + NA;
    const int total = 3 * E;
    const int K = (M + (1 << BSHIFT) - 1) >> BSHIFT;   // 586 for 300k dst rows

    // ---- workspace ----
    const size_t PL = (size_t)(NA + NB) * 64;
    u16* plane[2];
    plane[0] = (u16*)d_ws;
    plane[1] = plane[0] + PL;
    u16* wh     = plane[1] + PL;                 // 11*4096
    u16* meanB  = wh + 11 * 4096;
    u16* meanA1 = meanB + (size_t)NB * 64;
    u16* meanA2 = meanA1 + (size_t)NA * 64;
    int* gcursor= (int*)(meanA2 + (size_t)NA * 64); // K (alloc 1024)
    int* off_s  = gcursor + 1024;                // M
    int* off_e  = off_s + M;                     // M
    int* colidx = off_e + M;                     // K*CAP (bucket-padded)
    int* pairs  = (int*)meanB;                   // K*CAP, aliases means (dead until gathers)

    // ---- prep (convert + weights + cursor init) ----
    int bA = (NA * 16 + 255) / 256, bB = (NB * 16 + 255) / 256;
    prep_convert<<<bA + bB + 11 + 1, 256, 0, stream>>>(
        xA_in, xB_in, Wn, Wr, W_out, plane[0], wh, gcursor, NA, NB, K);

    // ---- CSR build: fixed-capacity buckets, scan-free partition ----
    int ntiles = (total + TILE - 1) / TILE;
    partition_kernel<<<ntiles, 1024, 0, stream>>>(src0, dst0, src1, dst1, src2, dst2,
                                                  gcursor, pairs, NB, NA, E, total);
    bucket_fill<<<K, 512, 0, stream>>>(pairs, gcursor, off_s, off_e, colidx, M);

    // ---- layer 1: gather + MFMA layer (bf16 plane out) ----
    const int blocksB = (NB + 63) / 64;
    const int blocksA = (NA + 63) / 64;
    gather_all<<<(M + 31) / 32, 256, 0, stream>>>(plane[0], colidx, off_s, off_e,
                                                  meanB, meanA1, meanA2, NB, NA);
    layer1_kernel<<<blocksB + blocksA, 256, 0, stream>>>(
        plane[0], plane[1], meanB, meanA1, meanA2, wh, b, NA, NB, blocksB);

    // ---- layer 2 + head fused (f32 out, no plane-2 write) ----
    gather_all<<<(M + 31) / 32, 256, 0, stream>>>(plane[1], colidx, off_s, off_e,
                                                  meanB, meanA1, meanA2, NB, NA);
    layer2_head_kernel<<<blocksB + blocksA, 256, 0, stream>>>(
        plane[1], meanB, meanA1, meanA2, wh, b, b_out, (float*)d_out, NA, NB, blocksB);
}